// Round 6
// baseline (292.575 us; speedup 1.0000x reference)
//
#include <hip/hip_runtime.h>
#include <hip/hip_bf16.h>

typedef __attribute__((ext_vector_type(8))) short short8;
typedef __attribute__((ext_vector_type(8))) unsigned short ushort8;
typedef __attribute__((ext_vector_type(4))) float floatx4;
typedef __attribute__((ext_vector_type(16))) float floatx16;
typedef __attribute__((ext_vector_type(4))) unsigned int uint4v;
typedef __attribute__((ext_vector_type(2))) unsigned int uint2v;

#define DEVINL static __device__ __forceinline__

DEVINL float b2f(unsigned short s){ union{unsigned u; float f;} v; v.u=((unsigned)s)<<16; return v.f; }
DEVINL unsigned fbits(float f){ union{float f; unsigned u;} v; v.f=f; return v.u; }
// pack two floats to bf16 pair (f0 -> low16, f1 -> high16), round-half-up via +0x8000
DEVINL unsigned pack2(float f0, float f1){
  return __builtin_amdgcn_perm(fbits(f1)+0x8000u, fbits(f0)+0x8000u, 0x07060302u);
}
DEVINL float tanh_fast(float v){
  float ax = fabsf(v);
  float ex = __expf(-2.f*ax);
  float th = (1.f - ex)*__builtin_amdgcn_rcpf(1.f + ex);
  return copysignf(th, v);
}

constexpr int Sc=256, Hc=768, Nc=128, HIDc=1024, Lc=16;

// ---------------- gather + bf16 cast: con[b*N+n][768] ----------------
__global__ __launch_bounds__(256) void k_gather(const float* __restrict__ AH,
                                                const int* __restrict__ ST,
                                                unsigned short* __restrict__ con){
  int row = blockIdx.x;            // b*128 + n
  int b = row >> 7;
  int st = ST[row];
  const float* src = AH + ((size_t)(b*Sc + st))*Hc;
  unsigned short* dst = con + (size_t)row*Hc;
  int t = threadIdx.x;
  if (t < 192) {
    float4 v = reinterpret_cast<const float4*>(src)[t];
    uint2v o = { pack2(v.x, v.y), pack2(v.z, v.w) };
    *reinterpret_cast<uint2v*>(dst + 4*t) = o;
  }
}

// ---------- W1m (rows 2304..3071 of W1) -> bf16 32x32x16-B-fragments ----------
// layout: [ht(32)][kc(48)][lane(64)][e(8)]; h = ht*32 + (l&31), k = kc*16 + (l>>5)*8 + e
__global__ __launch_bounds__(256) void k_w1m(const float* __restrict__ W1,
                                             unsigned short* __restrict__ w1mF){
  int sid = blockIdx.x*256 + threadIdx.x;     // 0..98303
  int l = sid & 63, kc = (sid >> 6) % 48, ht = sid / (48*64);
  int k = kc*16 + (l >> 5)*8;
  int h = ht*32 + (l & 31);
  const float* wp = W1 + (size_t)(2304 + k)*1024 + h;
  uint4v d;
  d[0] = pack2(wp[0],      wp[1024]);
  d[1] = pack2(wp[2*1024], wp[3*1024]);
  d[2] = pack2(wp[4*1024], wp[5*1024]);
  d[3] = pack2(wp[6*1024], wp[7*1024]);
  *reinterpret_cast<uint4v*>(w1mF + (size_t)sid*8) = d;
}

// ---------- W2 -> bf16 16x16x32-B-fragments ----------
// w2F: [hq(4)][ks(8)][lane(64)][e(8)]; col = l&15, k(h) = hq*256+ks*32+(l>>4)*8+e
__global__ __launch_bounds__(256) void k_w2(const float* __restrict__ W2,
                                            unsigned short* __restrict__ w2F){
  int gid = blockIdx.x*256 + threadIdx.x;    // 0..2047
  int l = gid & 63, ks = (gid >> 6) & 7, hq = gid >> 9;
  int h0 = hq*256 + ks*32 + (l >> 4)*8;
  const float* wp = W2 + (size_t)h0*Lc + (l & 15);
  uint4v d;
  d[0] = pack2(wp[0],    wp[16]);
  d[1] = pack2(wp[32],   wp[48]);
  d[2] = pack2(wp[64],   wp[80]);
  d[3] = pack2(wp[96],   wp[112]);
  *reinterpret_cast<uint4v*>(w2F + (size_t)gid*8) = d;
}

// ---------- combined P/Q weights -> bf16 fragments (16x16x32) ----------
__global__ __launch_bounds__(256) void k_wpq(const float* __restrict__ W1,
                                             unsigned short* __restrict__ wPQF){
  int sid = blockIdx.x*256 + threadIdx.x;     // 0..196607
  int lane = sid & 63, kcq = (sid >> 6) % 24, ht = sid / (24*64);
  int col = lane & 15, seg = lane >> 4;
  int hp = ht*16 + col;
  int kb = kcq*32 + seg*8;
  uint4v d;
  if (hp < 1024) {
    const float* w0 = W1 + (size_t)kb*1024 + hp;
    const float* wd = W1 + (size_t)(1536+kb)*1024 + hp;
    d[0] = pack2(w0[0]+wd[0],           w0[1024]+wd[1024]);
    d[1] = pack2(w0[2*1024]+wd[2*1024], w0[3*1024]+wd[3*1024]);
    d[2] = pack2(w0[4*1024]+wd[4*1024], w0[5*1024]+wd[5*1024]);
    d[3] = pack2(w0[6*1024]+wd[6*1024], w0[7*1024]+wd[7*1024]);
  } else {
    int hq = hp - 1024;
    const float* wc = W1 + (size_t)(768+kb)*1024 + hq;
    const float* wd = W1 + (size_t)(1536+kb)*1024 + hq;
    d[0] = pack2(wc[0]-wd[0],           wc[1024]-wd[1024]);
    d[1] = pack2(wc[2*1024]-wd[2*1024], wc[3*1024]-wd[3*1024]);
    d[2] = pack2(wc[4*1024]-wd[4*1024], wc[5*1024]-wd[5*1024]);
    d[3] = pack2(wc[6*1024]-wd[6*1024], wc[7*1024]-wd[7*1024]);
  }
  *reinterpret_cast<uint4v*>(wPQF + (size_t)sid*8) = d;
}

// ---------------- P/Q via MFMA: out[512 rows][2048 cols] ----------------
__global__ __launch_bounds__(256) void k_pq(const unsigned short* __restrict__ con,
                                            const unsigned short* __restrict__ wPQF,
                                            float* __restrict__ P, float* __restrict__ Q){
  int rg = blockIdx.x >> 4, hg = blockIdx.x & 15;     // 16 rowgroups x 16 colgroups
  int t = threadIdx.x, w = t >> 6, lane = t & 63;
  int colh = lane & 15, rseg = lane >> 4;
  floatx4 zero = {0.f,0.f,0.f,0.f};
  floatx4 acc[2][2] = {{zero,zero},{zero,zero}};
  const unsigned short* a0p = con + (size_t)(rg*32 + colh)*Hc + rseg*8;
  const unsigned short* a1p = a0p + 16*Hc;
  const unsigned short* b0p = wPQF + (((size_t)((hg*8 + w*2)*24)) << 9) + (lane << 3);
  const unsigned short* b1p = b0p + (24 << 9);
  #pragma unroll
  for (int kc = 0; kc < 24; ++kc) {
    short8 af0 = *reinterpret_cast<const short8*>(a0p + kc*32);
    short8 af1 = *reinterpret_cast<const short8*>(a1p + kc*32);
    short8 bf0 = *reinterpret_cast<const short8*>(b0p + ((size_t)kc << 9));
    short8 bf1 = *reinterpret_cast<const short8*>(b1p + ((size_t)kc << 9));
    acc[0][0] = __builtin_amdgcn_mfma_f32_16x16x32_bf16(af0, bf0, acc[0][0], 0,0,0);
    acc[0][1] = __builtin_amdgcn_mfma_f32_16x16x32_bf16(af0, bf1, acc[0][1], 0,0,0);
    acc[1][0] = __builtin_amdgcn_mfma_f32_16x16x32_bf16(af1, bf0, acc[1][0], 0,0,0);
    acc[1][1] = __builtin_amdgcn_mfma_f32_16x16x32_bf16(af1, bf1, acc[1][1], 0,0,0);
  }
  #pragma unroll
  for (int m = 0; m < 2; ++m)
    #pragma unroll
    for (int n = 0; n < 2; ++n)
      #pragma unroll
      for (int rr = 0; rr < 4; ++rr) {
        int row = rg*32 + m*16 + rseg*4 + rr;
        int hp = hg*128 + w*32 + n*16 + colh;
        float val = acc[m][n][rr];
        if (hg < 8) P[(size_t)row*HIDc + hp] = val;
        else        Q[(size_t)row*HIDc + (hp - 1024)] = val;
      }
}

// ---------------- fused main kernel: one block per (b,i) ----------------
// 512 blocks x 512 threads (8 waves), 2 blocks/CU (4 waves/SIMD).
// GEMM1: mfma_32x32x16, wave grid 2(j) x 4(h), wave tile 64j x 64h:
//   0.5 KB LDS-read per MFMA (2.25x less than r5). K staged 32/round.
// GEMM2: 16x16x32 per hq(256-h) chunk; hid exchanged via hidC uint layout
//   [j][wc][col] (bank-perfect writes), (j&3)-XOR swizzle on read.
__global__ __launch_bounds__(512, 4) void k_main(const unsigned short* __restrict__ con,
    const unsigned short* __restrict__ w1mF, const unsigned short* __restrict__ w2F,
    const float* __restrict__ P, const float* __restrict__ Q, const float* __restrict__ b1,
    const float* __restrict__ b2v, float* __restrict__ out){
  __shared__ __align__(16) char Xbuf[65536];     // A(8K)+B(16K) | hidC(64K)
  __shared__ float a_row[768];
  __shared__ float Pi_lds[1024];
  __shared__ unsigned short W2F_lds[8][64][8];

  typedef unsigned short tile_t[64][8];
  tile_t* A_lds = reinterpret_cast<tile_t*>(Xbuf);           // 8 tiles [kc2*4+jt]
  tile_t* B_lds = reinterpret_cast<tile_t*>(Xbuf + 8192);    // 16 tiles [kc2*8+ht]
  unsigned* hidC = reinterpret_cast<unsigned*>(Xbuf);        // [j(128)][wc(4)][col(32)]

  int bi = blockIdx.x, b = bi >> 7, i = bi & 127, bN = b*128;
  int t = threadIdx.x, w = t >> 6, lane = t & 63;
  int wr = w >> 2, wc = w & 3;
  int col = lane & 31, hi5 = lane >> 5;

  // A staging invariants: thread t stages tile (kc2A, jtA) lane
  int kc2A = t >> 8, jtA = (t >> 6) & 3;
  int jArow = jtA*32 + col;
  int koffA = kc2A*16 + hi5*8;
  const unsigned short* conA = con + (size_t)(bN + jArow)*Hc + koffA;
  unsigned short* Awr = &A_lds[kc2A*4 + jtA][lane][0];
  // B staging invariants: thread t stages tiles (kc2=0, ht=w) and (kc2=1, ht=w)
  unsigned short* Bwr0 = &B_lds[w][lane][0];
  unsigned short* Bwr1 = &B_lds[8 + w][lane][0];

  if (t < 384) {
    unsigned u = *reinterpret_cast<const unsigned*>(con + (size_t)(bN + i)*Hc + 2*t);
    a_row[2*t]   = b2f((unsigned short)(u & 0xffffu));
    a_row[2*t+1] = b2f((unsigned short)(u >> 16));
  }
  {
    int idx = t*2;
    const float* pp = P + (size_t)(bN + i)*HIDc;
    Pi_lds[idx]   = pp[idx]   + b1[idx];
    Pi_lds[idx+1] = pp[idx+1] + b1[idx+1];
  }

  floatx4 zero4 = {0.f,0.f,0.f,0.f};
  floatx4 acc2 = zero4;
  __syncthreads();

  for (int hq = 0; hq < 4; ++hq) {
    floatx16 acc[2][2];
    #pragma unroll
    for (int m = 0; m < 2; ++m)
      #pragma unroll
      for (int n = 0; n < 2; ++n)
        #pragma unroll
        for (int r = 0; r < 16; ++r) acc[m][n][r] = 0.f;

    for (int kr = 0; kr < 24; ++kr) {
      int kb = kr << 5;
      { // stage A (product) and B (copy)
        ushort8 ca = *reinterpret_cast<const ushort8*>(conA + kb);
        floatx4 av0 = *reinterpret_cast<const floatx4*>(&a_row[kb + koffA]);
        floatx4 av1 = *reinterpret_cast<const floatx4*>(&a_row[kb + koffA + 4]);
        uint4v dA;
        dA[0]=pack2(av0[0]*b2f(ca[0]), av0[1]*b2f(ca[1]));
        dA[1]=pack2(av0[2]*b2f(ca[2]), av0[3]*b2f(ca[3]));
        dA[2]=pack2(av1[0]*b2f(ca[4]), av1[1]*b2f(ca[5]));
        dA[3]=pack2(av1[2]*b2f(ca[6]), av1[3]*b2f(ca[7]));
        *reinterpret_cast<uint4v*>(Awr) = dA;
        size_t bo = (((size_t)(hq*8 + w)*48 + (kr << 1)) << 9) + (lane << 3);
        *reinterpret_cast<ushort8*>(Bwr0) = *reinterpret_cast<const ushort8*>(w1mF + bo);
        *reinterpret_cast<ushort8*>(Bwr1) = *reinterpret_cast<const ushort8*>(w1mF + bo + 512);
      }
      __syncthreads();
      { // kc2 = 0
        short8 a0 = *reinterpret_cast<const short8*>(&A_lds[wr*2    ][lane][0]);
        short8 a1 = *reinterpret_cast<const short8*>(&A_lds[wr*2 + 1][lane][0]);
        short8 f0 = *reinterpret_cast<const short8*>(&B_lds[wc*2    ][lane][0]);
        short8 f1 = *reinterpret_cast<const short8*>(&B_lds[wc*2 + 1][lane][0]);
        acc[0][0] = __builtin_amdgcn_mfma_f32_32x32x16_bf16(a0, f0, acc[0][0], 0,0,0);
        acc[0][1] = __builtin_amdgcn_mfma_f32_32x32x16_bf16(a0, f1, acc[0][1], 0,0,0);
        acc[1][0] = __builtin_amdgcn_mfma_f32_32x32x16_bf16(a1, f0, acc[1][0], 0,0,0);
        acc[1][1] = __builtin_amdgcn_mfma_f32_32x32x16_bf16(a1, f1, acc[1][1], 0,0,0);
      }
      { // kc2 = 1
        short8 a0 = *reinterpret_cast<const short8*>(&A_lds[4 + wr*2    ][lane][0]);
        short8 a1 = *reinterpret_cast<const short8*>(&A_lds[4 + wr*2 + 1][lane][0]);
        short8 f0 = *reinterpret_cast<const short8*>(&B_lds[8 + wc*2    ][lane][0]);
        short8 f1 = *reinterpret_cast<const short8*>(&B_lds[8 + wc*2 + 1][lane][0]);
        acc[0][0] = __builtin_amdgcn_mfma_f32_32x32x16_bf16(a0, f0, acc[0][0], 0,0,0);
        acc[0][1] = __builtin_amdgcn_mfma_f32_32x32x16_bf16(a0, f1, acc[0][1], 0,0,0);
        acc[1][0] = __builtin_amdgcn_mfma_f32_32x32x16_bf16(a1, f0, acc[1][0], 0,0,0);
        acc[1][1] = __builtin_amdgcn_mfma_f32_32x32x16_bf16(a1, f1, acc[1][1], 0,0,0);
      }
      __syncthreads();
    }

    // ---- epilogue: W2F stage + tanh -> hidC (union over A/B) ----
    *reinterpret_cast<ushort8*>(&W2F_lds[w][lane][0]) =
      *reinterpret_cast<const ushort8*>(w2F + (((size_t)(hq*8 + w)) << 9) + (lane << 3));

    float pb0 = Pi_lds[hq*256 + wc*64 + col];
    float pb1 = Pi_lds[hq*256 + wc*64 + 32 + col];
    #pragma unroll
    for (int m = 0; m < 2; ++m) {
      int jt32 = (wr*2 + m)*32;
      #pragma unroll
      for (int rq = 0; rq < 4; ++rq) {
        #pragma unroll
        for (int rr = 0; rr < 4; ++rr) {
          int reg = rq*4 + rr;
          int j = jt32 + rr + 8*rq + 4*hi5;
          const float* qp = Q + (size_t)(bN + j)*HIDc + hq*256 + wc*64 + col;
          float v0 = acc[m][0][reg] + pb0 + qp[0];
          float v1 = acc[m][1][reg] + pb1 + qp[32];
          hidC[((j*4 + wc) << 5) + (col ^ ((j & 3) << 3))] =
            pack2(tanh_fast(v0), tanh_fast(v1));
        }
      }
    }
    __syncthreads();

    // ---- GEMM2: wave w handles j-tile w ----
    {
      int j2 = (w << 4) + (lane & 15);
      int cbs = ((lane >> 4) << 3) ^ ((j2 & 3) << 3);
      const unsigned* hp = hidC + ((j2*4) << 5) + cbs;
      #pragma unroll
      for (int ks = 0; ks < 8; ++ks) {
        const uint4v* pp = reinterpret_cast<const uint4v*>(hp + ((ks >> 1) << 5));
        uint4v u0 = pp[0], u1 = pp[1];
        unsigned sel = (ks & 1) ? 0x07060302u : 0x05040100u;
        union { uint4v u; short8 s; } cvt;
        cvt.u[0] = __builtin_amdgcn_perm(u0[1], u0[0], sel);
        cvt.u[1] = __builtin_amdgcn_perm(u0[3], u0[2], sel);
        cvt.u[2] = __builtin_amdgcn_perm(u1[1], u1[0], sel);
        cvt.u[3] = __builtin_amdgcn_perm(u1[3], u1[2], sel);
        short8 wf = *reinterpret_cast<const short8*>(&W2F_lds[ks][lane][0]);
        acc2 = __builtin_amdgcn_mfma_f32_16x16x32_bf16(cvt.s, wf, acc2, 0,0,0);
      }
    }
    __syncthreads();
  }

  int l = lane & 15;
  float bl = b2v[l];
  #pragma unroll
  for (int r = 0; r < 4; ++r) {
    int jout = (w << 4) + ((lane >> 4) << 2) + r;
    out[((size_t)bi*Nc + jout)*Lc + l] = acc2[r] + bl;
  }
}

extern "C" void kernel_launch(void* const* d_in, const int* in_sizes, int n_in,
                              void* d_out, int out_size, void* d_ws, size_t ws_size,
                              hipStream_t stream) {
  const float* AH = (const float*)d_in[0];
  const int*   ST = (const int*)d_in[1];
  const float* W1 = (const float*)d_in[2];
  const float* b1 = (const float*)d_in[3];
  const float* W2 = (const float*)d_in[4];
  const float* b2 = (const float*)d_in[5];
  float* out = (float*)d_out;

  char* ws = (char*)d_ws;
  unsigned short* con  = (unsigned short*)ws;                //   786,432 B
  unsigned short* w1mF = (unsigned short*)(ws +   786432);   // 1,572,864 B
  unsigned short* wPQF = (unsigned short*)(ws +  2359296);   // 3,145,728 B
  float* P = (float*)(ws + 5505024);                         // 2,097,152 B
  float* Q = (float*)(ws + 7602176);                         // 2,097,152 B
  unsigned short* w2F  = (unsigned short*)(ws + 9699328);    //    32,768 B

  k_gather<<<512, 256, 0, stream>>>(AH, ST, con);
  k_w1m<<<384, 256, 0, stream>>>(W1, w1mF);
  k_w2<<<8, 256, 0, stream>>>(W2, w2F);
  k_wpq<<<768, 256, 0, stream>>>(W1, wPQF);
  k_pq<<<256, 256, 0, stream>>>(con, wPQF, P, Q);
  k_main<<<512, 512, 0, stream>>>(con, w1mF, w2F, P, Q, b1, b2, out);
}

// Round 7
// 202.402 us; speedup vs baseline: 1.4455x; 1.4455x over previous
//
#include <hip/hip_runtime.h>
#include <hip/hip_bf16.h>

typedef __attribute__((ext_vector_type(8))) short short8;
typedef __attribute__((ext_vector_type(8))) unsigned short ushort8;
typedef __attribute__((ext_vector_type(4))) float floatx4;
typedef __attribute__((ext_vector_type(16))) float floatx16;
typedef __attribute__((ext_vector_type(4))) unsigned int uint4v;
typedef __attribute__((ext_vector_type(2))) unsigned int uint2v;

#define DEVINL static __device__ __forceinline__

DEVINL float b2f(unsigned short s){ union{unsigned u; float f;} v; v.u=((unsigned)s)<<16; return v.f; }
DEVINL unsigned fbits(float f){ union{float f; unsigned u;} v; v.f=f; return v.u; }
// pack two floats to bf16 pair (f0 -> low16, f1 -> high16), round-half-up via +0x8000
DEVINL unsigned pack2(float f0, float f1){
  return __builtin_amdgcn_perm(fbits(f1)+0x8000u, fbits(f0)+0x8000u, 0x07060302u);
}
DEVINL float tanh_fast(float v){
  float ax = fabsf(v);
  float ex = __expf(-2.f*ax);
  float th = (1.f - ex)*__builtin_amdgcn_rcpf(1.f + ex);
  return copysignf(th, v);
}

constexpr int Sc=256, Hc=768, Nc=128, HIDc=1024, Lc=16;

// ---------------- gather + bf16 cast: con[b*N+n][768] ----------------
__global__ __launch_bounds__(256) void k_gather(const float* __restrict__ AH,
                                                const int* __restrict__ ST,
                                                unsigned short* __restrict__ con){
  int row = blockIdx.x;            // b*128 + n
  int b = row >> 7;
  int st = ST[row];
  const float* src = AH + ((size_t)(b*Sc + st))*Hc;
  unsigned short* dst = con + (size_t)row*Hc;
  int t = threadIdx.x;
  if (t < 192) {
    float4 v = reinterpret_cast<const float4*>(src)[t];
    uint2v o = { pack2(v.x, v.y), pack2(v.z, v.w) };
    *reinterpret_cast<uint2v*>(dst + 4*t) = o;
  }
}

// ---------- W1m (rows 2304..3071 of W1) -> bf16 32x32x16 fragments ----------
// layout: [ht(32)][kc(48)][lane(64)][e(8)]; h = ht*32 + (l&31), k = kc*16 + (l>>5)*8 + e
__global__ __launch_bounds__(256) void k_w1m(const float* __restrict__ W1,
                                             unsigned short* __restrict__ w1mF){
  int sid = blockIdx.x*256 + threadIdx.x;     // 0..98303
  int l = sid & 63, kc = (sid >> 6) % 48, ht = sid / (48*64);
  int k = kc*16 + (l >> 5)*8;
  int h = ht*32 + (l & 31);
  const float* wp = W1 + (size_t)(2304 + k)*1024 + h;
  uint4v d;
  d[0] = pack2(wp[0],      wp[1024]);
  d[1] = pack2(wp[2*1024], wp[3*1024]);
  d[2] = pack2(wp[4*1024], wp[5*1024]);
  d[3] = pack2(wp[6*1024], wp[7*1024]);
  *reinterpret_cast<uint4v*>(w1mF + (size_t)sid*8) = d;
}

// ---------- W2^T -> zero-padded 32x32x16 A-operand fragments ----------
// w2F2: [chunk(64)][lane(64)][e(8)]; row L = l&31 (>=16 -> 0),
// k-slot h = chunk*16 + 4*(l>>5) + (e&3) + 8*(e>>2)
__global__ __launch_bounds__(256) void k_w2t(const float* __restrict__ W2,
                                             unsigned short* __restrict__ w2F2){
  int gid = blockIdx.x*256 + threadIdx.x;    // 0..4095
  int l = gid & 63, chunk = gid >> 6;
  int row = l & 31, s = l >> 5;
  unsigned u[4];
  #pragma unroll
  for (int p = 0; p < 4; ++p) {
    int e0 = 2*p, e1 = 2*p + 1;
    int h0 = chunk*16 + 4*s + (e0 & 3) + 8*(e0 >> 2);
    int h1 = chunk*16 + 4*s + (e1 & 3) + 8*(e1 >> 2);
    float v0 = (row < 16) ? W2[(size_t)h0*Lc + row] : 0.f;
    float v1 = (row < 16) ? W2[(size_t)h1*Lc + row] : 0.f;
    u[p] = pack2(v0, v1);
  }
  uint4v d = { u[0], u[1], u[2], u[3] };
  *reinterpret_cast<uint4v*>(w2F2 + (size_t)gid*8) = d;
}

// ---------- combined P/Q weights -> bf16 fragments (16x16x32) ----------
__global__ __launch_bounds__(256) void k_wpq(const float* __restrict__ W1,
                                             unsigned short* __restrict__ wPQF){
  int sid = blockIdx.x*256 + threadIdx.x;     // 0..196607
  int lane = sid & 63, kcq = (sid >> 6) % 24, ht = sid / (24*64);
  int col = lane & 15, seg = lane >> 4;
  int hp = ht*16 + col;
  int kb = kcq*32 + seg*8;
  uint4v d;
  if (hp < 1024) {
    const float* w0 = W1 + (size_t)kb*1024 + hp;
    const float* wd = W1 + (size_t)(1536+kb)*1024 + hp;
    d[0] = pack2(w0[0]+wd[0],           w0[1024]+wd[1024]);
    d[1] = pack2(w0[2*1024]+wd[2*1024], w0[3*1024]+wd[3*1024]);
    d[2] = pack2(w0[4*1024]+wd[4*1024], w0[5*1024]+wd[5*1024]);
    d[3] = pack2(w0[6*1024]+wd[6*1024], w0[7*1024]+wd[7*1024]);
  } else {
    int hq = hp - 1024;
    const float* wc = W1 + (size_t)(768+kb)*1024 + hq;
    const float* wd = W1 + (size_t)(1536+kb)*1024 + hq;
    d[0] = pack2(wc[0]-wd[0],           wc[1024]-wd[1024]);
    d[1] = pack2(wc[2*1024]-wd[2*1024], wc[3*1024]-wd[3*1024]);
    d[2] = pack2(wc[4*1024]-wd[4*1024], wc[5*1024]-wd[5*1024]);
    d[3] = pack2(wc[6*1024]-wd[6*1024], wc[7*1024]-wd[7*1024]);
  }
  *reinterpret_cast<uint4v*>(wPQF + (size_t)sid*8) = d;
}

// ---------------- P/Q via MFMA: out[512 rows][2048 cols] ----------------
__global__ __launch_bounds__(256) void k_pq(const unsigned short* __restrict__ con,
                                            const unsigned short* __restrict__ wPQF,
                                            float* __restrict__ P, float* __restrict__ Q){
  int rg = blockIdx.x >> 4, hg = blockIdx.x & 15;     // 16 rowgroups x 16 colgroups
  int t = threadIdx.x, w = t >> 6, lane = t & 63;
  int colh = lane & 15, rseg = lane >> 4;
  floatx4 zero = {0.f,0.f,0.f,0.f};
  floatx4 acc[2][2] = {{zero,zero},{zero,zero}};
  const unsigned short* a0p = con + (size_t)(rg*32 + colh)*Hc + rseg*8;
  const unsigned short* a1p = a0p + 16*Hc;
  const unsigned short* b0p = wPQF + (((size_t)((hg*8 + w*2)*24)) << 9) + (lane << 3);
  const unsigned short* b1p = b0p + (24 << 9);
  #pragma unroll
  for (int kc = 0; kc < 24; ++kc) {
    short8 af0 = *reinterpret_cast<const short8*>(a0p + kc*32);
    short8 af1 = *reinterpret_cast<const short8*>(a1p + kc*32);
    short8 bf0 = *reinterpret_cast<const short8*>(b0p + ((size_t)kc << 9));
    short8 bf1 = *reinterpret_cast<const short8*>(b1p + ((size_t)kc << 9));
    acc[0][0] = __builtin_amdgcn_mfma_f32_16x16x32_bf16(af0, bf0, acc[0][0], 0,0,0);
    acc[0][1] = __builtin_amdgcn_mfma_f32_16x16x32_bf16(af0, bf1, acc[0][1], 0,0,0);
    acc[1][0] = __builtin_amdgcn_mfma_f32_16x16x32_bf16(af1, bf0, acc[1][0], 0,0,0);
    acc[1][1] = __builtin_amdgcn_mfma_f32_16x16x32_bf16(af1, bf1, acc[1][1], 0,0,0);
  }
  #pragma unroll
  for (int m = 0; m < 2; ++m)
    #pragma unroll
    for (int n = 0; n < 2; ++n)
      #pragma unroll
      for (int rr = 0; rr < 4; ++rr) {
        int row = rg*32 + m*16 + rseg*4 + rr;
        int hp = hg*128 + w*32 + n*16 + colh;
        float val = acc[m][n][rr];
        if (hg < 8) P[(size_t)row*HIDc + hp] = val;
        else        Q[(size_t)row*HIDc + (hp - 1024)] = val;
      }
}

// ---------------- fused main kernel: one block per (b,i,jhalf) ----------------
// 1024 blocks x 256 thr (4 waves), 4 blocks/CU. GEMM1 = swapped-operand
// 32x32x16: C^T[h][j] = mfma(w1m_frag, conprod_frag). Wave w owns h-tile w
// (32 h of the 128-h hc window) x all 64 j. Only the con-product goes through
// LDS (1 write + 4 reads/thread/K32); w1m fragments stream from global (L2).
// Epilogue: thread holds 16 h for fixed j -> GEMM2 fragment = reg order
// (frag[e]=tanh(acc[kc*8+e])), zero shuffle; GEMM2 = swapped 32x32x16 vs
// zero-padded W2^T frags; 16KB cross-wave reduction once at the end.
__global__ __launch_bounds__(256, 4) void k_main(const unsigned short* __restrict__ con,
    const unsigned short* __restrict__ w1mF, const unsigned short* __restrict__ w2F2,
    const float* __restrict__ P, const float* __restrict__ Q, const float* __restrict__ b1,
    const float* __restrict__ b2v, float* __restrict__ out){
  __shared__ float a_row[768];
  __shared__ float Pi_lds[1024];
  __shared__ __align__(16) unsigned short A_lds[4][64][8];   // [kc2*2+jt][lane][e]
  __shared__ __align__(16) float red[16][64][4];             // 16KB reduce buf

  int bid = blockIdx.x, jh = bid & 1, bi = bid >> 1;
  int b = bi >> 7, i = bi & 127, bN = b*128;
  int t = threadIdx.x, w = t >> 6, lane = t & 63;
  int col32 = lane & 31, hi5 = lane >> 5;

  // staging role: thread t stages tile (kc2A, jtA) at its lane
  int kc2A = t >> 7, jtA = (t >> 6) & 1;
  int jstage = jh*64 + jtA*32 + col32;
  int koffA = kc2A*16 + hi5*8;
  const unsigned short* conA = con + (size_t)(bN + jstage)*Hc + koffA;
  unsigned short* Awr = &A_lds[kc2A*2 + jtA][lane][0];

  if (t < 96) {
    ushort8 c8 = *reinterpret_cast<const ushort8*>(con + (size_t)(bN + i)*Hc + t*8);
    #pragma unroll
    for (int e = 0; e < 8; ++e) a_row[t*8 + e] = b2f((unsigned short)c8[e]);
  }
  {
    float4 p4 = reinterpret_cast<const float4*>(P + (size_t)(bN + i)*HIDc)[t];
    float4 b4 = reinterpret_cast<const float4*>(b1)[t];
    float4 s4 = { p4.x + b4.x, p4.y + b4.y, p4.z + b4.z, p4.w + b4.w };
    *reinterpret_cast<float4*>(&Pi_lds[4*t]) = s4;
  }

  floatx16 acc2[2];
  #pragma unroll
  for (int jt = 0; jt < 2; ++jt)
    #pragma unroll
    for (int r = 0; r < 16; ++r) acc2[jt][r] = 0.f;
  __syncthreads();

  for (int hc = 0; hc < 8; ++hc) {
    floatx16 acc[2];
    #pragma unroll
    for (int jt = 0; jt < 2; ++jt)
      #pragma unroll
      for (int r = 0; r < 16; ++r) acc[jt][r] = 0.f;

    const unsigned short* w1p = w1mF + (((size_t)((hc*4 + w)*48)) << 9) + (lane << 3);

    for (int kr = 0; kr < 24; ++kr) {
      // global fragment loads (issued early; consumed after barrier)
      ushort8 wx0 = *reinterpret_cast<const ushort8*>(w1p + (((size_t)(kr*2    )) << 9));
      ushort8 wx1 = *reinterpret_cast<const ushort8*>(w1p + (((size_t)(kr*2 + 1)) << 9));
      // stage con-product tile
      ushort8 ca = *reinterpret_cast<const ushort8*>(conA + kr*32);
      floatx4 av0 = *reinterpret_cast<const floatx4*>(&a_row[kr*32 + koffA]);
      floatx4 av1 = *reinterpret_cast<const floatx4*>(&a_row[kr*32 + koffA + 4]);
      uint4v dA;
      dA[0] = pack2(av0[0]*b2f(ca[0]), av0[1]*b2f(ca[1]));
      dA[1] = pack2(av0[2]*b2f(ca[2]), av0[3]*b2f(ca[3]));
      dA[2] = pack2(av1[0]*b2f(ca[4]), av1[1]*b2f(ca[5]));
      dA[3] = pack2(av1[2]*b2f(ca[6]), av1[3]*b2f(ca[7]));
      *reinterpret_cast<uint4v*>(Awr) = dA;
      __syncthreads();
      short8 y00 = *reinterpret_cast<const short8*>(&A_lds[0][lane][0]);  // kc2=0, jt0
      short8 y01 = *reinterpret_cast<const short8*>(&A_lds[1][lane][0]);  // kc2=0, jt1
      short8 y10 = *reinterpret_cast<const short8*>(&A_lds[2][lane][0]);  // kc2=1, jt0
      short8 y11 = *reinterpret_cast<const short8*>(&A_lds[3][lane][0]);  // kc2=1, jt1
      acc[0] = __builtin_amdgcn_mfma_f32_32x32x16_bf16(wx0, y00, acc[0], 0,0,0);
      acc[1] = __builtin_amdgcn_mfma_f32_32x32x16_bf16(wx0, y01, acc[1], 0,0,0);
      acc[0] = __builtin_amdgcn_mfma_f32_32x32x16_bf16(wx1, y10, acc[0], 0,0,0);
      acc[1] = __builtin_amdgcn_mfma_f32_32x32x16_bf16(wx1, y11, acc[1], 0,0,0);
      __syncthreads();
    }

    // ---- epilogue: tanh in-register -> GEMM2 fragments (zero shuffle) ----
    const unsigned short* w2p = w2F2 + (((size_t)(hc*8 + w*2)) << 9) + (lane << 3);
    ushort8 wf0 = *reinterpret_cast<const ushort8*>(w2p);
    ushort8 wf1 = *reinterpret_cast<const ushort8*>(w2p + 512);
    int hbase = hc*128 + w*32 + 4*hi5;

    #pragma unroll
    for (int jt = 0; jt < 2; ++jt) {
      const float* qrow = Q + (size_t)(bN + jh*64 + jt*32 + col32)*HIDc + hbase;
      unsigned hfu[2][4];
      #pragma unroll
      for (int q = 0; q < 4; ++q) {
        floatx4 qv = *reinterpret_cast<const floatx4*>(qrow + 8*q);
        floatx4 pf = *reinterpret_cast<const floatx4*>(&Pi_lds[hbase + 8*q]);
        float t0 = tanh_fast(acc[jt][q*4+0] + pf[0] + qv[0]);
        float t1 = tanh_fast(acc[jt][q*4+1] + pf[1] + qv[1]);
        float t2 = tanh_fast(acc[jt][q*4+2] + pf[2] + qv[2]);
        float t3 = tanh_fast(acc[jt][q*4+3] + pf[3] + qv[3]);
        hfu[q >> 1][(q & 1)*2 + 0] = pack2(t0, t1);
        hfu[q >> 1][(q & 1)*2 + 1] = pack2(t2, t3);
      }
      union { uint4v u; short8 s; } f0, f1;
      f0.u[0]=hfu[0][0]; f0.u[1]=hfu[0][1]; f0.u[2]=hfu[0][2]; f0.u[3]=hfu[0][3];
      f1.u[0]=hfu[1][0]; f1.u[1]=hfu[1][1]; f1.u[2]=hfu[1][2]; f1.u[3]=hfu[1][3];
      acc2[jt] = __builtin_amdgcn_mfma_f32_32x32x16_bf16(wf0, f0.s, acc2[jt], 0,0,0);
      acc2[jt] = __builtin_amdgcn_mfma_f32_32x32x16_bf16(wf1, f1.s, acc2[jt], 0,0,0);
    }
  }

  // ---- cross-wave reduction (only regs 0..7 carry L<16) ----
  #pragma unroll
  for (int jt = 0; jt < 2; ++jt)
    #pragma unroll
    for (int q = 0; q < 2; ++q) {
      floatx4 v = { acc2[jt][q*4+0], acc2[jt][q*4+1], acc2[jt][q*4+2], acc2[jt][q*4+3] };
      *reinterpret_cast<floatx4*>(&red[(w*2 + jt)*2 + q][lane][0]) = v;
    }
  __syncthreads();
  {
    int jtR = w & 1, qR = w >> 1;
    floatx4 s = {0.f,0.f,0.f,0.f};
    #pragma unroll
    for (int src = 0; src < 4; ++src) {
      floatx4 v = *reinterpret_cast<const floatx4*>(&red[(src*2 + jtR)*2 + qR][lane][0]);
      s[0]+=v[0]; s[1]+=v[1]; s[2]+=v[2]; s[3]+=v[3];
    }
    int jout = jh*64 + jtR*32 + col32;
    int Lb = 8*qR + 4*hi5;
    float* op = out + ((size_t)bi*Nc + jout)*Lc + Lb;
    #pragma unroll
    for (int c = 0; c < 4; ++c) op[c] = s[c] + b2v[Lb + c];
  }
}

extern "C" void kernel_launch(void* const* d_in, const int* in_sizes, int n_in,
                              void* d_out, int out_size, void* d_ws, size_t ws_size,
                              hipStream_t stream) {
  const float* AH = (const float*)d_in[0];
  const int*   ST = (const int*)d_in[1];
  const float* W1 = (const float*)d_in[2];
  const float* b1 = (const float*)d_in[3];
  const float* W2 = (const float*)d_in[4];
  const float* b2 = (const float*)d_in[5];
  float* out = (float*)d_out;

  char* ws = (char*)d_ws;
  unsigned short* con  = (unsigned short*)ws;                //   786,432 B
  unsigned short* w1mF = (unsigned short*)(ws +   786432);   // 1,572,864 B
  unsigned short* wPQF = (unsigned short*)(ws +  2359296);   // 3,145,728 B
  float* P = (float*)(ws + 5505024);                         // 2,097,152 B
  float* Q = (float*)(ws + 7602176);                         // 2,097,152 B
  unsigned short* w2F2 = (unsigned short*)(ws + 9699328);    //    65,536 B

  k_gather<<<512, 256, 0, stream>>>(AH, ST, con);
  k_w1m<<<384, 256, 0, stream>>>(W1, w1mF);
  k_w2t<<<16, 256, 0, stream>>>(W2, w2F2);
  k_wpq<<<768, 256, 0, stream>>>(W1, wPQF);
  k_pq<<<256, 256, 0, stream>>>(con, wPQF, P, Q);
  k_main<<<1024, 256, 0, stream>>>(con, w1mF, w2F2, P, Q, b1, b2, out);
}

// Round 8
// 189.435 us; speedup vs baseline: 1.5445x; 1.0685x over previous
//
#include <hip/hip_runtime.h>
#include <hip/hip_bf16.h>

typedef __attribute__((ext_vector_type(8))) short short8;
typedef __attribute__((ext_vector_type(8))) unsigned short ushort8;
typedef __attribute__((ext_vector_type(4))) float floatx4;
typedef __attribute__((ext_vector_type(16))) float floatx16;
typedef __attribute__((ext_vector_type(4))) unsigned int uint4v;
typedef __attribute__((ext_vector_type(2))) unsigned int uint2v;

#define DEVINL static __device__ __forceinline__

DEVINL float b2f(unsigned short s){ union{unsigned u; float f;} v; v.u=((unsigned)s)<<16; return v.f; }
DEVINL unsigned fbits(float f){ union{float f; unsigned u;} v; v.f=f; return v.u; }
// pack two floats to bf16 pair (f0 -> low16, f1 -> high16), round-half-up via +0x8000
DEVINL unsigned pack2(float f0, float f1){
  return __builtin_amdgcn_perm(fbits(f1)+0x8000u, fbits(f0)+0x8000u, 0x07060302u);
}
DEVINL float tanh_fast(float v){
  float ax = fabsf(v);
  float ex = __expf(-2.f*ax);
  float th = (1.f - ex)*__builtin_amdgcn_rcpf(1.f + ex);
  return copysignf(th, v);
}

constexpr int Sc=256, Hc=768, Nc=128, HIDc=1024, Lc=16;

// ---------------- gather + bf16 cast: con[b*N+n][768] ----------------
__global__ __launch_bounds__(256) void k_gather(const float* __restrict__ AH,
                                                const int* __restrict__ ST,
                                                unsigned short* __restrict__ con){
  int row = blockIdx.x;            // b*128 + n
  int b = row >> 7;
  int st = ST[row];
  const float* src = AH + ((size_t)(b*Sc + st))*Hc;
  unsigned short* dst = con + (size_t)row*Hc;
  int t = threadIdx.x;
  if (t < 192) {
    float4 v = reinterpret_cast<const float4*>(src)[t];
    uint2v o = { pack2(v.x, v.y), pack2(v.z, v.w) };
    *reinterpret_cast<uint2v*>(dst + 4*t) = o;
  }
}

// ---------- W1m (rows 2304..3071 of W1) -> bf16 32x32x16 fragments ----------
// layout: [ht(32)][kc(48)][lane(64)][e(8)]; h = ht*32 + (l&31), k = kc*16 + (l>>5)*8 + e
__global__ __launch_bounds__(256) void k_w1m(const float* __restrict__ W1,
                                             unsigned short* __restrict__ w1mF){
  int sid = blockIdx.x*256 + threadIdx.x;     // 0..98303
  int l = sid & 63, kc = (sid >> 6) % 48, ht = sid / (48*64);
  int k = kc*16 + (l >> 5)*8;
  int h = ht*32 + (l & 31);
  const float* wp = W1 + (size_t)(2304 + k)*1024 + h;
  uint4v d;
  d[0] = pack2(wp[0],      wp[1024]);
  d[1] = pack2(wp[2*1024], wp[3*1024]);
  d[2] = pack2(wp[4*1024], wp[5*1024]);
  d[3] = pack2(wp[6*1024], wp[7*1024]);
  *reinterpret_cast<uint4v*>(w1mF + (size_t)sid*8) = d;
}

// ---------- W2^T -> zero-padded 32x32x16 A-operand fragments ----------
// w2F2: [chunk(64)][lane(64)][e(8)]; row L = l&31 (>=16 -> 0),
// k-slot h = chunk*16 + 4*(l>>5) + (e&3) + 8*(e>>2)
__global__ __launch_bounds__(256) void k_w2t(const float* __restrict__ W2,
                                             unsigned short* __restrict__ w2F2){
  int gid = blockIdx.x*256 + threadIdx.x;    // 0..4095
  int l = gid & 63, chunk = gid >> 6;
  int row = l & 31, s = l >> 5;
  unsigned u[4];
  #pragma unroll
  for (int p = 0; p < 4; ++p) {
    int e0 = 2*p, e1 = 2*p + 1;
    int h0 = chunk*16 + 4*s + (e0 & 3) + 8*(e0 >> 2);
    int h1 = chunk*16 + 4*s + (e1 & 3) + 8*(e1 >> 2);
    float v0 = (row < 16) ? W2[(size_t)h0*Lc + row] : 0.f;
    float v1 = (row < 16) ? W2[(size_t)h1*Lc + row] : 0.f;
    u[p] = pack2(v0, v1);
  }
  uint4v d = { u[0], u[1], u[2], u[3] };
  *reinterpret_cast<uint4v*>(w2F2 + (size_t)gid*8) = d;
}

// ---------- combined P/Q weights -> bf16 fragments (16x16x32) ----------
__global__ __launch_bounds__(256) void k_wpq(const float* __restrict__ W1,
                                             unsigned short* __restrict__ wPQF){
  int sid = blockIdx.x*256 + threadIdx.x;     // 0..196607
  int lane = sid & 63, kcq = (sid >> 6) % 24, ht = sid / (24*64);
  int col = lane & 15, seg = lane >> 4;
  int hp = ht*16 + col;
  int kb = kcq*32 + seg*8;
  uint4v d;
  if (hp < 1024) {
    const float* w0 = W1 + (size_t)kb*1024 + hp;
    const float* wd = W1 + (size_t)(1536+kb)*1024 + hp;
    d[0] = pack2(w0[0]+wd[0],           w0[1024]+wd[1024]);
    d[1] = pack2(w0[2*1024]+wd[2*1024], w0[3*1024]+wd[3*1024]);
    d[2] = pack2(w0[4*1024]+wd[4*1024], w0[5*1024]+wd[5*1024]);
    d[3] = pack2(w0[6*1024]+wd[6*1024], w0[7*1024]+wd[7*1024]);
  } else {
    int hq = hp - 1024;
    const float* wc = W1 + (size_t)(768+kb)*1024 + hq;
    const float* wd = W1 + (size_t)(1536+kb)*1024 + hq;
    d[0] = pack2(wc[0]-wd[0],           wc[1024]-wd[1024]);
    d[1] = pack2(wc[2*1024]-wd[2*1024], wc[3*1024]-wd[3*1024]);
    d[2] = pack2(wc[4*1024]-wd[4*1024], wc[5*1024]-wd[5*1024]);
    d[3] = pack2(wc[6*1024]-wd[6*1024], wc[7*1024]-wd[7*1024]);
  }
  *reinterpret_cast<uint4v*>(wPQF + (size_t)sid*8) = d;
}

// ---------------- P/Q via MFMA: out[512 rows][2048 cols] ----------------
__global__ __launch_bounds__(256) void k_pq(const unsigned short* __restrict__ con,
                                            const unsigned short* __restrict__ wPQF,
                                            float* __restrict__ P, float* __restrict__ Q){
  int rg = blockIdx.x >> 4, hg = blockIdx.x & 15;     // 16 rowgroups x 16 colgroups
  int t = threadIdx.x, w = t >> 6, lane = t & 63;
  int colh = lane & 15, rseg = lane >> 4;
  floatx4 zero = {0.f,0.f,0.f,0.f};
  floatx4 acc[2][2] = {{zero,zero},{zero,zero}};
  const unsigned short* a0p = con + (size_t)(rg*32 + colh)*Hc + rseg*8;
  const unsigned short* a1p = a0p + 16*Hc;
  const unsigned short* b0p = wPQF + (((size_t)((hg*8 + w*2)*24)) << 9) + (lane << 3);
  const unsigned short* b1p = b0p + (24 << 9);
  #pragma unroll
  for (int kc = 0; kc < 24; ++kc) {
    short8 af0 = *reinterpret_cast<const short8*>(a0p + kc*32);
    short8 af1 = *reinterpret_cast<const short8*>(a1p + kc*32);
    short8 bf0 = *reinterpret_cast<const short8*>(b0p + ((size_t)kc << 9));
    short8 bf1 = *reinterpret_cast<const short8*>(b1p + ((size_t)kc << 9));
    acc[0][0] = __builtin_amdgcn_mfma_f32_16x16x32_bf16(af0, bf0, acc[0][0], 0,0,0);
    acc[0][1] = __builtin_amdgcn_mfma_f32_16x16x32_bf16(af0, bf1, acc[0][1], 0,0,0);
    acc[1][0] = __builtin_amdgcn_mfma_f32_16x16x32_bf16(af1, bf0, acc[1][0], 0,0,0);
    acc[1][1] = __builtin_amdgcn_mfma_f32_16x16x32_bf16(af1, bf1, acc[1][1], 0,0,0);
  }
  #pragma unroll
  for (int m = 0; m < 2; ++m)
    #pragma unroll
    for (int n = 0; n < 2; ++n)
      #pragma unroll
      for (int rr = 0; rr < 4; ++rr) {
        int row = rg*32 + m*16 + rseg*4 + rr;
        int hp = hg*128 + w*32 + n*16 + colh;
        float val = acc[m][n][rr];
        if (hg < 8) P[(size_t)row*HIDc + hp] = val;
        else        Q[(size_t)row*HIDc + (hp - 1024)] = val;
      }
}

// ---------------- fused main kernel: one block per (b,i,jhalf) ----------------
// r7 structure with 256-h windows: wave owns 64 h (2 ht tiles) x 64 j ->
// acc 2x2 floatx16 (64 AGPR). Per K32 round: SAME staging cost as r7 but
// 8 MFMAs (2x the MFMA:overhead ratio); rounds 192->96, barriers 384->192.
// B (w1m) frags stream from global/L2 (r7-proven); wx pair for kc2=1 issued
// after the barrier, hidden under kc2=0's MFMAs (caps VGPR).
__global__ __launch_bounds__(256, 3) void k_main(const unsigned short* __restrict__ con,
    const unsigned short* __restrict__ w1mF, const unsigned short* __restrict__ w2F2,
    const float* __restrict__ P, const float* __restrict__ Q, const float* __restrict__ b1,
    const float* __restrict__ b2v, float* __restrict__ out){
  __shared__ float a_row[768];
  __shared__ float Pi_lds[1024];
  __shared__ __align__(16) unsigned short A_lds[4][64][8];   // [kc2*2+jt][lane][e]
  __shared__ __align__(16) float red[16][64][4];             // 16KB reduce buf

  int bid = blockIdx.x, jh = bid & 1, bi = bid >> 1;
  int b = bi >> 7, i = bi & 127, bN = b*128;
  int t = threadIdx.x, w = t >> 6, lane = t & 63;
  int col32 = lane & 31, hi5 = lane >> 5;

  // staging role: thread t stages tile (kc2A, jtA) at its lane
  int kc2A = t >> 7, jtA = (t >> 6) & 1;
  int jstage = jh*64 + jtA*32 + col32;
  int koffA = kc2A*16 + hi5*8;
  const unsigned short* conA = con + (size_t)(bN + jstage)*Hc + koffA;
  unsigned short* Awr = &A_lds[kc2A*2 + jtA][lane][0];

  if (t < 96) {
    ushort8 c8 = *reinterpret_cast<const ushort8*>(con + (size_t)(bN + i)*Hc + t*8);
    #pragma unroll
    for (int e = 0; e < 8; ++e) a_row[t*8 + e] = b2f((unsigned short)c8[e]);
  }
  {
    float4 p4 = reinterpret_cast<const float4*>(P + (size_t)(bN + i)*HIDc)[t];
    float4 b4 = reinterpret_cast<const float4*>(b1)[t];
    float4 s4 = { p4.x + b4.x, p4.y + b4.y, p4.z + b4.z, p4.w + b4.w };
    *reinterpret_cast<float4*>(&Pi_lds[4*t]) = s4;
  }

  floatx16 acc2_0, acc2_1;
  #pragma unroll
  for (int r = 0; r < 16; ++r) { acc2_0[r] = 0.f; acc2_1[r] = 0.f; }
  __syncthreads();

  for (int hc = 0; hc < 4; ++hc) {
    floatx16 acc00, acc01, acc10, acc11;   // [ht][jt]
    #pragma unroll
    for (int r = 0; r < 16; ++r) { acc00[r]=0.f; acc01[r]=0.f; acc10[r]=0.f; acc11[r]=0.f; }

    // wave w owns h tiles htg0 = hc*8 + w*2 (+0,+1)
    const unsigned short* w1p0 = w1mF + (((size_t)((hc*8 + w*2)*48)) << 9) + (lane << 3);
    const unsigned short* w1p1 = w1p0 + ((size_t)48 << 9);

    for (int kr = 0; kr < 24; ++kr) {
      // kc2=0 B-frags issued early (latency hidden under staging+barrier)
      ushort8 wxA0 = *reinterpret_cast<const ushort8*>(w1p0 + (((size_t)(kr*2)) << 9));
      ushort8 wxB0 = *reinterpret_cast<const ushort8*>(w1p1 + (((size_t)(kr*2)) << 9));
      // stage con-product tile
      ushort8 ca = *reinterpret_cast<const ushort8*>(conA + kr*32);
      floatx4 av0 = *reinterpret_cast<const floatx4*>(&a_row[kr*32 + koffA]);
      floatx4 av1 = *reinterpret_cast<const floatx4*>(&a_row[kr*32 + koffA + 4]);
      uint4v dA;
      dA[0] = pack2(av0[0]*b2f(ca[0]), av0[1]*b2f(ca[1]));
      dA[1] = pack2(av0[2]*b2f(ca[2]), av0[3]*b2f(ca[3]));
      dA[2] = pack2(av1[0]*b2f(ca[4]), av1[1]*b2f(ca[5]));
      dA[3] = pack2(av1[2]*b2f(ca[6]), av1[3]*b2f(ca[7]));
      *reinterpret_cast<uint4v*>(Awr) = dA;
      __syncthreads();
      // kc2=1 B-frags issued now, consumed after kc2=0 MFMAs
      ushort8 wxA1 = *reinterpret_cast<const ushort8*>(w1p0 + (((size_t)(kr*2+1)) << 9));
      ushort8 wxB1 = *reinterpret_cast<const ushort8*>(w1p1 + (((size_t)(kr*2+1)) << 9));
      {
        short8 y00 = *reinterpret_cast<const short8*>(&A_lds[0][lane][0]);  // kc2=0, jt0
        short8 y01 = *reinterpret_cast<const short8*>(&A_lds[1][lane][0]);  // kc2=0, jt1
        acc00 = __builtin_amdgcn_mfma_f32_32x32x16_bf16(wxA0, y00, acc00, 0,0,0);
        acc01 = __builtin_amdgcn_mfma_f32_32x32x16_bf16(wxA0, y01, acc01, 0,0,0);
        acc10 = __builtin_amdgcn_mfma_f32_32x32x16_bf16(wxB0, y00, acc10, 0,0,0);
        acc11 = __builtin_amdgcn_mfma_f32_32x32x16_bf16(wxB0, y01, acc11, 0,0,0);
      }
      {
        short8 y10 = *reinterpret_cast<const short8*>(&A_lds[2][lane][0]);  // kc2=1, jt0
        short8 y11 = *reinterpret_cast<const short8*>(&A_lds[3][lane][0]);  // kc2=1, jt1
        acc00 = __builtin_amdgcn_mfma_f32_32x32x16_bf16(wxA1, y10, acc00, 0,0,0);
        acc01 = __builtin_amdgcn_mfma_f32_32x32x16_bf16(wxA1, y11, acc01, 0,0,0);
        acc10 = __builtin_amdgcn_mfma_f32_32x32x16_bf16(wxB1, y10, acc10, 0,0,0);
        acc11 = __builtin_amdgcn_mfma_f32_32x32x16_bf16(wxB1, y11, acc11, 0,0,0);
      }
      __syncthreads();
    }

    // ---- epilogue per ht: tanh in-register -> GEMM2 (zero shuffle) ----
    #pragma unroll
    for (int ht = 0; ht < 2; ++ht) {
      int htg = hc*8 + w*2 + ht;
      const unsigned short* w2p = w2F2 + (((size_t)(htg*2)) << 9) + (lane << 3);
      ushort8 wf0 = *reinterpret_cast<const ushort8*>(w2p);
      ushort8 wf1 = *reinterpret_cast<const ushort8*>(w2p + 512);
      int hbase = htg*32 + 4*hi5;
      #pragma unroll
      for (int jt = 0; jt < 2; ++jt) {
        const floatx16& a = (ht==0) ? (jt==0 ? acc00 : acc01)
                                    : (jt==0 ? acc10 : acc11);
        floatx16& a2 = (jt==0) ? acc2_0 : acc2_1;
        const float* qrow = Q + (size_t)(bN + jh*64 + jt*32 + col32)*HIDc + hbase;
        unsigned hfu[2][4];
        #pragma unroll
        for (int q = 0; q < 4; ++q) {
          floatx4 qv = *reinterpret_cast<const floatx4*>(qrow + 8*q);
          floatx4 pf = *reinterpret_cast<const floatx4*>(&Pi_lds[hbase + 8*q]);
          float t0 = tanh_fast(a[q*4+0] + pf[0] + qv[0]);
          float t1 = tanh_fast(a[q*4+1] + pf[1] + qv[1]);
          float t2 = tanh_fast(a[q*4+2] + pf[2] + qv[2]);
          float t3 = tanh_fast(a[q*4+3] + pf[3] + qv[3]);
          hfu[q >> 1][(q & 1)*2 + 0] = pack2(t0, t1);
          hfu[q >> 1][(q & 1)*2 + 1] = pack2(t2, t3);
        }
        union { uint4v u; short8 s; } f0, f1;
        f0.u[0]=hfu[0][0]; f0.u[1]=hfu[0][1]; f0.u[2]=hfu[0][2]; f0.u[3]=hfu[0][3];
        f1.u[0]=hfu[1][0]; f1.u[1]=hfu[1][1]; f1.u[2]=hfu[1][2]; f1.u[3]=hfu[1][3];
        a2 = __builtin_amdgcn_mfma_f32_32x32x16_bf16(wf0, f0.s, a2, 0,0,0);
        a2 = __builtin_amdgcn_mfma_f32_32x32x16_bf16(wf1, f1.s, a2, 0,0,0);
      }
    }
  }

  // ---- cross-wave reduction (only regs 0..7 carry L<16) ----
  #pragma unroll
  for (int q = 0; q < 2; ++q) {
    floatx4 v0 = { acc2_0[q*4+0], acc2_0[q*4+1], acc2_0[q*4+2], acc2_0[q*4+3] };
    floatx4 v1 = { acc2_1[q*4+0], acc2_1[q*4+1], acc2_1[q*4+2], acc2_1[q*4+3] };
    *reinterpret_cast<floatx4*>(&red[(w*2 + 0)*2 + q][lane][0]) = v0;
    *reinterpret_cast<floatx4*>(&red[(w*2 + 1)*2 + q][lane][0]) = v1;
  }
  __syncthreads();
  {
    int jtR = w & 1, qR = w >> 1;
    floatx4 s = {0.f,0.f,0.f,0.f};
    #pragma unroll
    for (int src = 0; src < 4; ++src) {
      floatx4 v = *reinterpret_cast<const floatx4*>(&red[(src*2 + jtR)*2 + qR][lane][0]);
      s[0]+=v[0]; s[1]+=v[1]; s[2]+=v[2]; s[3]+=v[3];
    }
    int jout = jh*64 + jtR*32 + col32;
    int Lb = 8*qR + 4*hi5;
    float* op = out + ((size_t)bi*Nc + jout)*Lc + Lb;
    #pragma unroll
    for (int c = 0; c < 4; ++c) op[c] = s[c] + b2v[Lb + c];
  }
}

extern "C" void kernel_launch(void* const* d_in, const int* in_sizes, int n_in,
                              void* d_out, int out_size, void* d_ws, size_t ws_size,
                              hipStream_t stream) {
  const float* AH = (const float*)d_in[0];
  const int*   ST = (const int*)d_in[1];
  const float* W1 = (const float*)d_in[2];
  const float* b1 = (const float*)d_in[3];
  const float* W2 = (const float*)d_in[4];
  const float* b2 = (const float*)d_in[5];
  float* out = (float*)d_out;

  char* ws = (char*)d_ws;
  unsigned short* con  = (unsigned short*)ws;                //   786,432 B
  unsigned short* w1mF = (unsigned short*)(ws +   786432);   // 1,572,864 B
  unsigned short* wPQF = (unsigned short*)(ws +  2359296);   // 3,145,728 B
  float* P = (float*)(ws + 5505024);                         // 2,097,152 B
  float* Q = (float*)(ws + 7602176);                         // 2,097,152 B
  unsigned short* w2F2 = (unsigned short*)(ws + 9699328);    //    65,536 B

  k_gather<<<512, 256, 0, stream>>>(AH, ST, con);
  k_w1m<<<384, 256, 0, stream>>>(W1, w1mF);
  k_w2t<<<16, 256, 0, stream>>>(W2, w2F2);
  k_wpq<<<768, 256, 0, stream>>>(W1, wPQF);
  k_pq<<<256, 256, 0, stream>>>(con, wPQF, P, Q);
  k_main<<<1024, 256, 0, stream>>>(con, w1mF, w2F2, P, Q, b1, b2, out);
}

// Round 9
// 169.071 us; speedup vs baseline: 1.7305x; 1.1204x over previous
//
#include <hip/hip_runtime.h>
#include <hip/hip_bf16.h>

typedef __attribute__((ext_vector_type(8))) short short8;
typedef __attribute__((ext_vector_type(8))) unsigned short ushort8;
typedef __attribute__((ext_vector_type(4))) float floatx4;
typedef __attribute__((ext_vector_type(16))) float floatx16;
typedef __attribute__((ext_vector_type(4))) unsigned int uint4v;
typedef __attribute__((ext_vector_type(2))) unsigned int uint2v;

#define DEVINL static __device__ __forceinline__

DEVINL float b2f(unsigned short s){ union{unsigned u; float f;} v; v.u=((unsigned)s)<<16; return v.f; }
DEVINL unsigned fbits(float f){ union{float f; unsigned u;} v; v.f=f; return v.u; }
// pack two floats to bf16 pair (f0 -> low16, f1 -> high16), round-half-up via +0x8000
DEVINL unsigned pack2(float f0, float f1){
  return __builtin_amdgcn_perm(fbits(f1)+0x8000u, fbits(f0)+0x8000u, 0x07060302u);
}
DEVINL float tanh_fast(float v){
  float ax = fabsf(v);
  float ex = __expf(-2.f*ax);
  float th = (1.f - ex)*__builtin_amdgcn_rcpf(1.f + ex);
  return copysignf(th, v);
}

constexpr int Sc=256, Hc=768, Nc=128, HIDc=1024, Lc=16;

// ---------------- gather + bf16 cast: con[b*N+n][768] ----------------
__global__ __launch_bounds__(256) void k_gather(const float* __restrict__ AH,
                                                const int* __restrict__ ST,
                                                unsigned short* __restrict__ con){
  int row = blockIdx.x;            // b*128 + n
  int b = row >> 7;
  int st = ST[row];
  const float* src = AH + ((size_t)(b*Sc + st))*Hc;
  unsigned short* dst = con + (size_t)row*Hc;
  int t = threadIdx.x;
  if (t < 192) {
    float4 v = reinterpret_cast<const float4*>(src)[t];
    uint2v o = { pack2(v.x, v.y), pack2(v.z, v.w) };
    *reinterpret_cast<uint2v*>(dst + 4*t) = o;
  }
}

// ---------- W1m (rows 2304..3071 of W1) -> bf16 32x32x16 fragments ----------
// layout: [ht(32)][kc(48)][lane(64)][e(8)]; h = ht*32 + (l&31), k = kc*16 + (l>>5)*8 + e
__global__ __launch_bounds__(256) void k_w1m(const float* __restrict__ W1,
                                             unsigned short* __restrict__ w1mF){
  int sid = blockIdx.x*256 + threadIdx.x;     // 0..98303
  int l = sid & 63, kc = (sid >> 6) % 48, ht = sid / (48*64);
  int k = kc*16 + (l >> 5)*8;
  int h = ht*32 + (l & 31);
  const float* wp = W1 + (size_t)(2304 + k)*1024 + h;
  uint4v d;
  d[0] = pack2(wp[0],      wp[1024]);
  d[1] = pack2(wp[2*1024], wp[3*1024]);
  d[2] = pack2(wp[4*1024], wp[5*1024]);
  d[3] = pack2(wp[6*1024], wp[7*1024]);
  *reinterpret_cast<uint4v*>(w1mF + (size_t)sid*8) = d;
}

// ---------- W2^T -> zero-padded 32x32x16 A-operand fragments ----------
// w2F2: [chunk(64)][lane(64)][e(8)]; row L = l&31 (>=16 -> 0),
// k-slot h = chunk*16 + 4*(l>>5) + (e&3) + 8*(e>>2)
__global__ __launch_bounds__(256) void k_w2t(const float* __restrict__ W2,
                                             unsigned short* __restrict__ w2F2){
  int gid = blockIdx.x*256 + threadIdx.x;    // 0..4095
  int l = gid & 63, chunk = gid >> 6;
  int row = l & 31, s = l >> 5;
  unsigned u[4];
  #pragma unroll
  for (int p = 0; p < 4; ++p) {
    int e0 = 2*p, e1 = 2*p + 1;
    int h0 = chunk*16 + 4*s + (e0 & 3) + 8*(e0 >> 2);
    int h1 = chunk*16 + 4*s + (e1 & 3) + 8*(e1 >> 2);
    float v0 = (row < 16) ? W2[(size_t)h0*Lc + row] : 0.f;
    float v1 = (row < 16) ? W2[(size_t)h1*Lc + row] : 0.f;
    u[p] = pack2(v0, v1);
  }
  uint4v d = { u[0], u[1], u[2], u[3] };
  *reinterpret_cast<uint4v*>(w2F2 + (size_t)gid*8) = d;
}

// ---------- combined P/Q weights -> bf16 fragments (16x16x32) ----------
__global__ __launch_bounds__(256) void k_wpq(const float* __restrict__ W1,
                                             unsigned short* __restrict__ wPQF){
  int sid = blockIdx.x*256 + threadIdx.x;     // 0..196607
  int lane = sid & 63, kcq = (sid >> 6) % 24, ht = sid / (24*64);
  int col = lane & 15, seg = lane >> 4;
  int hp = ht*16 + col;
  int kb = kcq*32 + seg*8;
  uint4v d;
  if (hp < 1024) {
    const float* w0 = W1 + (size_t)kb*1024 + hp;
    const float* wd = W1 + (size_t)(1536+kb)*1024 + hp;
    d[0] = pack2(w0[0]+wd[0],           w0[1024]+wd[1024]);
    d[1] = pack2(w0[2*1024]+wd[2*1024], w0[3*1024]+wd[3*1024]);
    d[2] = pack2(w0[4*1024]+wd[4*1024], w0[5*1024]+wd[5*1024]);
    d[3] = pack2(w0[6*1024]+wd[6*1024], w0[7*1024]+wd[7*1024]);
  } else {
    int hq = hp - 1024;
    const float* wc = W1 + (size_t)(768+kb)*1024 + hq;
    const float* wd = W1 + (size_t)(1536+kb)*1024 + hq;
    d[0] = pack2(wc[0]-wd[0],           wc[1024]-wd[1024]);
    d[1] = pack2(wc[2*1024]-wd[2*1024], wc[3*1024]-wd[3*1024]);
    d[2] = pack2(wc[4*1024]-wd[4*1024], wc[5*1024]-wd[5*1024]);
    d[3] = pack2(wc[6*1024]-wd[6*1024], wc[7*1024]-wd[7*1024]);
  }
  *reinterpret_cast<uint4v*>(wPQF + (size_t)sid*8) = d;
}

// ---------------- P/Q via MFMA: out[512 rows][2048 cols] ----------------
__global__ __launch_bounds__(256) void k_pq(const unsigned short* __restrict__ con,
                                            const unsigned short* __restrict__ wPQF,
                                            float* __restrict__ P, float* __restrict__ Q){
  int rg = blockIdx.x >> 4, hg = blockIdx.x & 15;     // 16 rowgroups x 16 colgroups
  int t = threadIdx.x, w = t >> 6, lane = t & 63;
  int colh = lane & 15, rseg = lane >> 4;
  floatx4 zero = {0.f,0.f,0.f,0.f};
  floatx4 acc[2][2] = {{zero,zero},{zero,zero}};
  const unsigned short* a0p = con + (size_t)(rg*32 + colh)*Hc + rseg*8;
  const unsigned short* a1p = a0p + 16*Hc;
  const unsigned short* b0p = wPQF + (((size_t)((hg*8 + w*2)*24)) << 9) + (lane << 3);
  const unsigned short* b1p = b0p + (24 << 9);
  #pragma unroll
  for (int kc = 0; kc < 24; ++kc) {
    short8 af0 = *reinterpret_cast<const short8*>(a0p + kc*32);
    short8 af1 = *reinterpret_cast<const short8*>(a1p + kc*32);
    short8 bf0 = *reinterpret_cast<const short8*>(b0p + ((size_t)kc << 9));
    short8 bf1 = *reinterpret_cast<const short8*>(b1p + ((size_t)kc << 9));
    acc[0][0] = __builtin_amdgcn_mfma_f32_16x16x32_bf16(af0, bf0, acc[0][0], 0,0,0);
    acc[0][1] = __builtin_amdgcn_mfma_f32_16x16x32_bf16(af0, bf1, acc[0][1], 0,0,0);
    acc[1][0] = __builtin_amdgcn_mfma_f32_16x16x32_bf16(af1, bf0, acc[1][0], 0,0,0);
    acc[1][1] = __builtin_amdgcn_mfma_f32_16x16x32_bf16(af1, bf1, acc[1][1], 0,0,0);
  }
  #pragma unroll
  for (int m = 0; m < 2; ++m)
    #pragma unroll
    for (int n = 0; n < 2; ++n)
      #pragma unroll
      for (int rr = 0; rr < 4; ++rr) {
        int row = rg*32 + m*16 + rseg*4 + rr;
        int hp = hg*128 + w*32 + n*16 + colh;
        float val = acc[m][n][rr];
        if (hg < 8) P[(size_t)row*HIDc + hp] = val;
        else        Q[(size_t)row*HIDc + (hp - 1024)] = val;
      }
}

// ---------------- fused main kernel: one block per (b,i,jhalf) ----------------
// r8 structure + software pipeline: double-buffered A_lds, ONE barrier/round,
// wx(kr+2) prefetched after this round's MFMAs (full-round cover), ca/av(kr+2)
// prefetched at round start. Parity-named prefetch regs (no reg arrays).
__global__ __launch_bounds__(256, 2) void k_main(const unsigned short* __restrict__ con,
    const unsigned short* __restrict__ w1mF, const unsigned short* __restrict__ w2F2,
    const float* __restrict__ P, const float* __restrict__ Q, const float* __restrict__ b1,
    const float* __restrict__ b2v, float* __restrict__ out){
  __shared__ float a_row[768];
  __shared__ float Pi_lds[1024];
  __shared__ __align__(16) unsigned short A_lds[2][4][64][8];   // double-buffered, 8KB
  __shared__ __align__(16) float red[16][64][4];                // 16KB reduce buf

  int bid = blockIdx.x, jh = bid & 1, bi = bid >> 1;
  int b = bi >> 7, i = bi & 127, bN = b*128;
  int t = threadIdx.x, w = t >> 6, lane = t & 63;
  int col32 = lane & 31, hi5 = lane >> 5;

  // staging role: thread t stages tile (kc2A, jtA) at its lane
  int kc2A = t >> 7, jtA = (t >> 6) & 1;
  int jstage = jh*64 + jtA*32 + col32;
  int koffA = kc2A*16 + hi5*8;
  const unsigned short* conA = con + (size_t)(bN + jstage)*Hc + koffA;
  unsigned short* Awr0 = &A_lds[0][kc2A*2 + jtA][lane][0];
  unsigned short* Awr1 = &A_lds[1][kc2A*2 + jtA][lane][0];

  if (t < 96) {
    ushort8 c8 = *reinterpret_cast<const ushort8*>(con + (size_t)(bN + i)*Hc + t*8);
    #pragma unroll
    for (int e = 0; e < 8; ++e) a_row[t*8 + e] = b2f((unsigned short)c8[e]);
  }
  {
    float4 p4 = reinterpret_cast<const float4*>(P + (size_t)(bN + i)*HIDc)[t];
    float4 b4 = reinterpret_cast<const float4*>(b1)[t];
    float4 s4 = { p4.x + b4.x, p4.y + b4.y, p4.z + b4.z, p4.w + b4.w };
    *reinterpret_cast<float4*>(&Pi_lds[4*t]) = s4;
  }

  floatx16 acc2_0, acc2_1;
  #pragma unroll
  for (int r = 0; r < 16; ++r) { acc2_0[r] = 0.f; acc2_1[r] = 0.f; }
  __syncthreads();

#define LOADWX(S0,S1,S2,S3, KR) { \
  size_t o_ = ((size_t)((KR)*2)) << 9; \
  S0 = *reinterpret_cast<const ushort8*>(w1p0 + o_); \
  S1 = *reinterpret_cast<const ushort8*>(w1p0 + o_ + 512); \
  S2 = *reinterpret_cast<const ushort8*>(w1p1 + o_); \
  S3 = *reinterpret_cast<const ushort8*>(w1p1 + o_ + 512); }

#define LOADCAV(CA, AV0, AV1, KR) { \
  int k_ = (KR) <= 23 ? (KR) : 23; \
  CA  = *reinterpret_cast<const ushort8*>(conA + k_*32); \
  AV0 = *reinterpret_cast<const floatx4*>(&a_row[k_*32 + koffA]); \
  AV1 = *reinterpret_cast<const floatx4*>(&a_row[k_*32 + koffA + 4]); }

#define PACKWRITE(DST, CA, AV0, AV1) { \
  uint4v dA_; \
  dA_[0] = pack2(AV0[0]*b2f(CA[0]), AV0[1]*b2f(CA[1])); \
  dA_[1] = pack2(AV0[2]*b2f(CA[2]), AV0[3]*b2f(CA[3])); \
  dA_[2] = pack2(AV1[0]*b2f(CA[4]), AV1[1]*b2f(CA[5])); \
  dA_[3] = pack2(AV1[2]*b2f(CA[6]), AV1[3]*b2f(CA[7])); \
  *reinterpret_cast<uint4v*>(DST) = dA_; }

#define MFMA8(BUF, S0,S1,S2,S3) { \
  short8 y00 = *reinterpret_cast<const short8*>(&A_lds[BUF][0][lane][0]); \
  short8 y01 = *reinterpret_cast<const short8*>(&A_lds[BUF][1][lane][0]); \
  short8 y10 = *reinterpret_cast<const short8*>(&A_lds[BUF][2][lane][0]); \
  short8 y11 = *reinterpret_cast<const short8*>(&A_lds[BUF][3][lane][0]); \
  acc00 = __builtin_amdgcn_mfma_f32_32x32x16_bf16(S0, y00, acc00, 0,0,0); \
  acc01 = __builtin_amdgcn_mfma_f32_32x32x16_bf16(S0, y01, acc01, 0,0,0); \
  acc10 = __builtin_amdgcn_mfma_f32_32x32x16_bf16(S2, y00, acc10, 0,0,0); \
  acc11 = __builtin_amdgcn_mfma_f32_32x32x16_bf16(S2, y01, acc11, 0,0,0); \
  acc00 = __builtin_amdgcn_mfma_f32_32x32x16_bf16(S1, y10, acc00, 0,0,0); \
  acc01 = __builtin_amdgcn_mfma_f32_32x32x16_bf16(S1, y11, acc01, 0,0,0); \
  acc10 = __builtin_amdgcn_mfma_f32_32x32x16_bf16(S3, y10, acc10, 0,0,0); \
  acc11 = __builtin_amdgcn_mfma_f32_32x32x16_bf16(S3, y11, acc11, 0,0,0); }

  for (int hc = 0; hc < 4; ++hc) {
    floatx16 acc00, acc01, acc10, acc11;   // [ht][jt]
    #pragma unroll
    for (int r = 0; r < 16; ++r) { acc00[r]=0.f; acc01[r]=0.f; acc10[r]=0.f; acc11[r]=0.f; }

    // wave w owns h tiles htg0 = hc*8 + w*2 (+0,+1)
    const unsigned short* w1p0 = w1mF + (((size_t)((hc*8 + w*2)*48)) << 9) + (lane << 3);
    const unsigned short* w1p1 = w1p0 + ((size_t)48 << 9);

    ushort8 caE, caO, wxS0, wxS1, wxS2, wxS3, vxS0, vxS1, vxS2, vxS3;
    floatx4 avE0, avE1, avO0, avO1;

    // prologue: product(0)->buf0; prefetch ca/av(1), wx(0), wx(1)
    LOADCAV(caE, avE0, avE1, 0);
    LOADCAV(caO, avO0, avO1, 1);
    LOADWX(wxS0, wxS1, wxS2, wxS3, 0);
    LOADWX(vxS0, vxS1, vxS2, vxS3, 1);
    PACKWRITE(Awr0, caE, avE0, avE1);
    __syncthreads();

    for (int krp = 0; krp < 12; ++krp) {
      { // EVEN round kr = 2*krp: read buf0, write product(kr+1)->buf1
        const int kr = 2*krp;
        LOADCAV(caE, avE0, avE1, kr+2);
        PACKWRITE(Awr1, caO, avO0, avO1);
        MFMA8(0, wxS0, wxS1, wxS2, wxS3);
        if (kr < 22) LOADWX(wxS0, wxS1, wxS2, wxS3, kr+2);
        __syncthreads();
      }
      { // ODD round kr = 2*krp+1: read buf1, write product(kr+1)->buf0
        const int kr = 2*krp + 1;
        if (kr < 23) {
          LOADCAV(caO, avO0, avO1, kr+2);
          PACKWRITE(Awr0, caE, avE0, avE1);
        }
        MFMA8(1, vxS0, vxS1, vxS2, vxS3);
        if (kr < 22) LOADWX(vxS0, vxS1, vxS2, vxS3, kr+2);
        __syncthreads();
      }
    }

    // ---- epilogue per ht: tanh in-register -> GEMM2 (zero shuffle) ----
    #pragma unroll
    for (int ht = 0; ht < 2; ++ht) {
      int htg = hc*8 + w*2 + ht;
      const unsigned short* w2p = w2F2 + (((size_t)(htg*2)) << 9) + (lane << 3);
      ushort8 wf0 = *reinterpret_cast<const ushort8*>(w2p);
      ushort8 wf1 = *reinterpret_cast<const ushort8*>(w2p + 512);
      int hbase = htg*32 + 4*hi5;
      #pragma unroll
      for (int jt = 0; jt < 2; ++jt) {
        const floatx16& a = (ht==0) ? (jt==0 ? acc00 : acc01)
                                    : (jt==0 ? acc10 : acc11);
        floatx16& a2 = (jt==0) ? acc2_0 : acc2_1;
        const float* qrow = Q + (size_t)(bN + jh*64 + jt*32 + col32)*HIDc + hbase;
        unsigned hfu[2][4];
        #pragma unroll
        for (int q = 0; q < 4; ++q) {
          floatx4 qv = *reinterpret_cast<const floatx4*>(qrow + 8*q);
          floatx4 pf = *reinterpret_cast<const floatx4*>(&Pi_lds[hbase + 8*q]);
          float t0 = tanh_fast(a[q*4+0] + pf[0] + qv[0]);
          float t1 = tanh_fast(a[q*4+1] + pf[1] + qv[1]);
          float t2 = tanh_fast(a[q*4+2] + pf[2] + qv[2]);
          float t3 = tanh_fast(a[q*4+3] + pf[3] + qv[3]);
          hfu[q >> 1][(q & 1)*2 + 0] = pack2(t0, t1);
          hfu[q >> 1][(q & 1)*2 + 1] = pack2(t2, t3);
        }
        union { uint4v u; short8 s; } f0, f1;
        f0.u[0]=hfu[0][0]; f0.u[1]=hfu[0][1]; f0.u[2]=hfu[0][2]; f0.u[3]=hfu[0][3];
        f1.u[0]=hfu[1][0]; f1.u[1]=hfu[1][1]; f1.u[2]=hfu[1][2]; f1.u[3]=hfu[1][3];
        a2 = __builtin_amdgcn_mfma_f32_32x32x16_bf16(wf0, f0.s, a2, 0,0,0);
        a2 = __builtin_amdgcn_mfma_f32_32x32x16_bf16(wf1, f1.s, a2, 0,0,0);
      }
    }
  }
#undef LOADWX
#undef LOADCAV
#undef PACKWRITE
#undef MFMA8

  // ---- cross-wave reduction (only regs 0..7 carry L<16) ----
  #pragma unroll
  for (int q = 0; q < 2; ++q) {
    floatx4 v0 = { acc2_0[q*4+0], acc2_0[q*4+1], acc2_0[q*4+2], acc2_0[q*4+3] };
    floatx4 v1 = { acc2_1[q*4+0], acc2_1[q*4+1], acc2_1[q*4+2], acc2_1[q*4+3] };
    *reinterpret_cast<floatx4*>(&red[(w*2 + 0)*2 + q][lane][0]) = v0;
    *reinterpret_cast<floatx4*>(&red[(w*2 + 1)*2 + q][lane][0]) = v1;
  }
  __syncthreads();
  {
    int jtR = w & 1, qR = w >> 1;
    floatx4 s = {0.f,0.f,0.f,0.f};
    #pragma unroll
    for (int src = 0; src < 4; ++src) {
      floatx4 v = *reinterpret_cast<const floatx4*>(&red[(src*2 + jtR)*2 + qR][lane][0]);
      s[0]+=v[0]; s[1]+=v[1]; s[2]+=v[2]; s[3]+=v[3];
    }
    int jout = jh*64 + jtR*32 + col32;
    int Lb = 8*qR + 4*hi5;
    float* op = out + ((size_t)bi*Nc + jout)*Lc + Lb;
    #pragma unroll
    for (int c = 0; c < 4; ++c) op[c] = s[c] + b2v[Lb + c];
  }
}

extern "C" void kernel_launch(void* const* d_in, const int* in_sizes, int n_in,
                              void* d_out, int out_size, void* d_ws, size_t ws_size,
                              hipStream_t stream) {
  const float* AH = (const float*)d_in[0];
  const int*   ST = (const int*)d_in[1];
  const float* W1 = (const float*)d_in[2];
  const float* b1 = (const float*)d_in[3];
  const float* W2 = (const float*)d_in[4];
  const float* b2 = (const float*)d_in[5];
  float* out = (float*)d_out;

  char* ws = (char*)d_ws;
  unsigned short* con  = (unsigned short*)ws;                //   786,432 B
  unsigned short* w1mF = (unsigned short*)(ws +   786432);   // 1,572,864 B
  unsigned short* wPQF = (unsigned short*)(ws +  2359296);   // 3,145,728 B
  float* P = (float*)(ws + 5505024);                         // 2,097,152 B
  float* Q = (float*)(ws + 7602176);                         // 2,097,152 B
  unsigned short* w2F2 = (unsigned short*)(ws + 9699328);    //    65,536 B

  k_gather<<<512, 256, 0, stream>>>(AH, ST, con);
  k_w1m<<<384, 256, 0, stream>>>(W1, w1mF);
  k_w2t<<<16, 256, 0, stream>>>(W2, w2F2);
  k_wpq<<<768, 256, 0, stream>>>(W1, wPQF);
  k_pq<<<256, 256, 0, stream>>>(con, wPQF, P, Q);
  k_main<<<1024, 256, 0, stream>>>(con, w1mF, w2F2, P, Q, b1, b2, out);
}

// Round 10
// 156.113 us; speedup vs baseline: 1.8741x; 1.0830x over previous
//
#include <hip/hip_runtime.h>
#include <hip/hip_bf16.h>

typedef __attribute__((ext_vector_type(8))) short short8;
typedef __attribute__((ext_vector_type(8))) unsigned short ushort8;
typedef __attribute__((ext_vector_type(4))) float floatx4;
typedef __attribute__((ext_vector_type(16))) float floatx16;
typedef __attribute__((ext_vector_type(4))) unsigned int uint4v;
typedef __attribute__((ext_vector_type(2))) unsigned int uint2v;

#define DEVINL static __device__ __forceinline__

DEVINL float b2f(unsigned short s){ union{unsigned u; float f;} v; v.u=((unsigned)s)<<16; return v.f; }
DEVINL unsigned fbits(float f){ union{float f; unsigned u;} v; v.f=f; return v.u; }
// pack two floats to bf16 pair (f0 -> low16, f1 -> high16), round-half-up via +0x8000
DEVINL unsigned pack2(float f0, float f1){
  return __builtin_amdgcn_perm(fbits(f1)+0x8000u, fbits(f0)+0x8000u, 0x07060302u);
}
// single-instruction packed cvt (RNE), gfx950 (T12-verified)
DEVINL unsigned cvt_pk(float lo, float hi){
  unsigned r;
  asm("v_cvt_pk_bf16_f32 %0, %1, %2" : "=v"(r) : "v"(lo), "v"(hi));
  return r;
}
// tanh(x) = 1 - 2/(1+e^{2x}); exact limits at +-inf; 3 VALU + 2 trans
DEVINL float tanh_fast(float v){
  float ex = __builtin_amdgcn_exp2f(v * 2.885390081777927f);   // e^{2v}
  return 1.f - 2.f*__builtin_amdgcn_rcpf(1.f + ex);
}

constexpr int Sc=256, Hc=768, Nc=128, HIDc=1024, Lc=16;

// ================= merged prep kernel =================
// bid <  512 : gather+cast con
// bid <  896 : W1m -> 32x32x16 fragments
// bid <  912 : W2^T -> zero-padded 32x32x16 A-operand fragments
// else       : combined P/Q weights -> 16x16x32 fragments
__global__ __launch_bounds__(256) void k_prep(const float* __restrict__ AH,
                                              const int* __restrict__ ST,
                                              const float* __restrict__ W1,
                                              const float* __restrict__ W2,
                                              unsigned short* __restrict__ con,
                                              unsigned short* __restrict__ w1mF,
                                              unsigned short* __restrict__ w2F2,
                                              unsigned short* __restrict__ wPQF){
  int bid = blockIdx.x, t = threadIdx.x;
  if (bid < 512) {
    int row = bid;                      // b*128 + n
    int b = row >> 7;
    int st = ST[row];
    const float* src = AH + ((size_t)(b*Sc + st))*Hc;
    unsigned short* dst = con + (size_t)row*Hc;
    if (t < 192) {
      float4 v = reinterpret_cast<const float4*>(src)[t];
      uint2v o = { pack2(v.x, v.y), pack2(v.z, v.w) };
      *reinterpret_cast<uint2v*>(dst + 4*t) = o;
    }
  } else if (bid < 896) {
    int sid = (bid - 512)*256 + t;      // 0..98303
    int l = sid & 63, kc = (sid >> 6) % 48, ht = sid / (48*64);
    int k = kc*16 + (l >> 5)*8;
    int h = ht*32 + (l & 31);
    const float* wp = W1 + (size_t)(2304 + k)*1024 + h;
    uint4v d;
    d[0] = pack2(wp[0],      wp[1024]);
    d[1] = pack2(wp[2*1024], wp[3*1024]);
    d[2] = pack2(wp[4*1024], wp[5*1024]);
    d[3] = pack2(wp[6*1024], wp[7*1024]);
    *reinterpret_cast<uint4v*>(w1mF + (size_t)sid*8) = d;
  } else if (bid < 912) {
    int gid = (bid - 896)*256 + t;      // 0..4095
    int l = gid & 63, chunk = gid >> 6;
    int row = l & 31, s = l >> 5;
    unsigned u[4];
    #pragma unroll
    for (int p = 0; p < 4; ++p) {
      int e0 = 2*p, e1 = 2*p + 1;
      int h0 = chunk*16 + 4*s + (e0 & 3) + 8*(e0 >> 2);
      int h1 = chunk*16 + 4*s + (e1 & 3) + 8*(e1 >> 2);
      float v0 = (row < 16) ? W2[(size_t)h0*Lc + row] : 0.f;
      float v1 = (row < 16) ? W2[(size_t)h1*Lc + row] : 0.f;
      u[p] = pack2(v0, v1);
    }
    uint4v d = { u[0], u[1], u[2], u[3] };
    *reinterpret_cast<uint4v*>(w2F2 + (size_t)gid*8) = d;
  } else {
    int sid = (bid - 912)*256 + t;      // 0..196607
    int lane = sid & 63, kcq = (sid >> 6) % 24, ht = sid / (24*64);
    int col = lane & 15, seg = lane >> 4;
    int hp = ht*16 + col;
    int kb = kcq*32 + seg*8;
    uint4v d;
    if (hp < 1024) {
      const float* w0 = W1 + (size_t)kb*1024 + hp;
      const float* wd = W1 + (size_t)(1536+kb)*1024 + hp;
      d[0] = pack2(w0[0]+wd[0],           w0[1024]+wd[1024]);
      d[1] = pack2(w0[2*1024]+wd[2*1024], w0[3*1024]+wd[3*1024]);
      d[2] = pack2(w0[4*1024]+wd[4*1024], w0[5*1024]+wd[5*1024]);
      d[3] = pack2(w0[6*1024]+wd[6*1024], w0[7*1024]+wd[7*1024]);
    } else {
      int hq = hp - 1024;
      const float* wc = W1 + (size_t)(768+kb)*1024 + hq;
      const float* wd = W1 + (size_t)(1536+kb)*1024 + hq;
      d[0] = pack2(wc[0]-wd[0],           wc[1024]-wd[1024]);
      d[1] = pack2(wc[2*1024]-wd[2*1024], wc[3*1024]-wd[3*1024]);
      d[2] = pack2(wc[4*1024]-wd[4*1024], wc[5*1024]-wd[5*1024]);
      d[3] = pack2(wc[6*1024]-wd[6*1024], wc[7*1024]-wd[7*1024]);
    }
    *reinterpret_cast<uint4v*>(wPQF + (size_t)sid*8) = d;
  }
}

// ---------------- P/Q via MFMA: out[512 rows][2048 cols] ----------------
__global__ __launch_bounds__(256) void k_pq(const unsigned short* __restrict__ con,
                                            const unsigned short* __restrict__ wPQF,
                                            float* __restrict__ P, float* __restrict__ Q){
  int rg = blockIdx.x >> 4, hg = blockIdx.x & 15;     // 16 rowgroups x 16 colgroups
  int t = threadIdx.x, w = t >> 6, lane = t & 63;
  int colh = lane & 15, rseg = lane >> 4;
  floatx4 zero = {0.f,0.f,0.f,0.f};
  floatx4 acc[2][2] = {{zero,zero},{zero,zero}};
  const unsigned short* a0p = con + (size_t)(rg*32 + colh)*Hc + rseg*8;
  const unsigned short* a1p = a0p + 16*Hc;
  const unsigned short* b0p = wPQF + (((size_t)((hg*8 + w*2)*24)) << 9) + (lane << 3);
  const unsigned short* b1p = b0p + (24 << 9);
  #pragma unroll
  for (int kc = 0; kc < 24; ++kc) {
    short8 af0 = *reinterpret_cast<const short8*>(a0p + kc*32);
    short8 af1 = *reinterpret_cast<const short8*>(a1p + kc*32);
    short8 bf0 = *reinterpret_cast<const short8*>(b0p + ((size_t)kc << 9));
    short8 bf1 = *reinterpret_cast<const short8*>(b1p + ((size_t)kc << 9));
    acc[0][0] = __builtin_amdgcn_mfma_f32_16x16x32_bf16(af0, bf0, acc[0][0], 0,0,0);
    acc[0][1] = __builtin_amdgcn_mfma_f32_16x16x32_bf16(af0, bf1, acc[0][1], 0,0,0);
    acc[1][0] = __builtin_amdgcn_mfma_f32_16x16x32_bf16(af1, bf0, acc[1][0], 0,0,0);
    acc[1][1] = __builtin_amdgcn_mfma_f32_16x16x32_bf16(af1, bf1, acc[1][1], 0,0,0);
  }
  #pragma unroll
  for (int m = 0; m < 2; ++m)
    #pragma unroll
    for (int n = 0; n < 2; ++n)
      #pragma unroll
      for (int rr = 0; rr < 4; ++rr) {
        int row = rg*32 + m*16 + rseg*4 + rr;
        int hp = hg*128 + w*32 + n*16 + colh;
        float val = acc[m][n][rr];
        if (hg < 8) P[(size_t)row*HIDc + hp] = val;
        else        Q[(size_t)row*HIDc + (hp - 1024)] = val;
      }
}

// ---------------- fused main kernel: one block per (b,i,jhalf) ----------------
// r9 pipelined structure + VALU diet: v_cvt_pk_bf16_f32 for all f32->bf16x2
// packing (3 ops -> 1) and cheap tanh (1-2/(1+e^2x), 3 VALU + 2 trans).
__global__ __launch_bounds__(256, 2) void k_main(const unsigned short* __restrict__ con,
    const unsigned short* __restrict__ w1mF, const unsigned short* __restrict__ w2F2,
    const float* __restrict__ P, const float* __restrict__ Q, const float* __restrict__ b1,
    const float* __restrict__ b2v, float* __restrict__ out){
  __shared__ float a_row[768];
  __shared__ float Pi_lds[1024];
  __shared__ __align__(16) unsigned short A_lds[2][4][64][8];   // double-buffered, 8KB
  __shared__ __align__(16) float red[16][64][4];                // 16KB reduce buf

  int bid = blockIdx.x, jh = bid & 1, bi = bid >> 1;
  int b = bi >> 7, i = bi & 127, bN = b*128;
  int t = threadIdx.x, w = t >> 6, lane = t & 63;
  int col32 = lane & 31, hi5 = lane >> 5;

  // staging role: thread t stages tile (kc2A, jtA) at its lane
  int kc2A = t >> 7, jtA = (t >> 6) & 1;
  int jstage = jh*64 + jtA*32 + col32;
  int koffA = kc2A*16 + hi5*8;
  const unsigned short* conA = con + (size_t)(bN + jstage)*Hc + koffA;
  unsigned short* Awr0 = &A_lds[0][kc2A*2 + jtA][lane][0];
  unsigned short* Awr1 = &A_lds[1][kc2A*2 + jtA][lane][0];

  if (t < 96) {
    ushort8 c8 = *reinterpret_cast<const ushort8*>(con + (size_t)(bN + i)*Hc + t*8);
    #pragma unroll
    for (int e = 0; e < 8; ++e) a_row[t*8 + e] = b2f((unsigned short)c8[e]);
  }
  {
    float4 p4 = reinterpret_cast<const float4*>(P + (size_t)(bN + i)*HIDc)[t];
    float4 b4 = reinterpret_cast<const float4*>(b1)[t];
    float4 s4 = { p4.x + b4.x, p4.y + b4.y, p4.z + b4.z, p4.w + b4.w };
    *reinterpret_cast<float4*>(&Pi_lds[4*t]) = s4;
  }

  floatx16 acc2_0, acc2_1;
  #pragma unroll
  for (int r = 0; r < 16; ++r) { acc2_0[r] = 0.f; acc2_1[r] = 0.f; }
  __syncthreads();

#define LOADWX(S0,S1,S2,S3, KR) { \
  size_t o_ = ((size_t)((KR)*2)) << 9; \
  S0 = *reinterpret_cast<const ushort8*>(w1p0 + o_); \
  S1 = *reinterpret_cast<const ushort8*>(w1p0 + o_ + 512); \
  S2 = *reinterpret_cast<const ushort8*>(w1p1 + o_); \
  S3 = *reinterpret_cast<const ushort8*>(w1p1 + o_ + 512); }

#define LOADCAV(CA, AV0, AV1, KR) { \
  int k_ = (KR) <= 23 ? (KR) : 23; \
  CA  = *reinterpret_cast<const ushort8*>(conA + k_*32); \
  AV0 = *reinterpret_cast<const floatx4*>(&a_row[k_*32 + koffA]); \
  AV1 = *reinterpret_cast<const floatx4*>(&a_row[k_*32 + koffA + 4]); }

#define PACKWRITE(DST, CA, AV0, AV1) { \
  uint4v dA_; \
  dA_[0] = cvt_pk(AV0[0]*b2f(CA[0]), AV0[1]*b2f(CA[1])); \
  dA_[1] = cvt_pk(AV0[2]*b2f(CA[2]), AV0[3]*b2f(CA[3])); \
  dA_[2] = cvt_pk(AV1[0]*b2f(CA[4]), AV1[1]*b2f(CA[5])); \
  dA_[3] = cvt_pk(AV1[2]*b2f(CA[6]), AV1[3]*b2f(CA[7])); \
  *reinterpret_cast<uint4v*>(DST) = dA_; }

#define MFMA8(BUF, S0,S1,S2,S3) { \
  short8 y00 = *reinterpret_cast<const short8*>(&A_lds[BUF][0][lane][0]); \
  short8 y01 = *reinterpret_cast<const short8*>(&A_lds[BUF][1][lane][0]); \
  short8 y10 = *reinterpret_cast<const short8*>(&A_lds[BUF][2][lane][0]); \
  short8 y11 = *reinterpret_cast<const short8*>(&A_lds[BUF][3][lane][0]); \
  acc00 = __builtin_amdgcn_mfma_f32_32x32x16_bf16(S0, y00, acc00, 0,0,0); \
  acc01 = __builtin_amdgcn_mfma_f32_32x32x16_bf16(S0, y01, acc01, 0,0,0); \
  acc10 = __builtin_amdgcn_mfma_f32_32x32x16_bf16(S2, y00, acc10, 0,0,0); \
  acc11 = __builtin_amdgcn_mfma_f32_32x32x16_bf16(S2, y01, acc11, 0,0,0); \
  acc00 = __builtin_amdgcn_mfma_f32_32x32x16_bf16(S1, y10, acc00, 0,0,0); \
  acc01 = __builtin_amdgcn_mfma_f32_32x32x16_bf16(S1, y11, acc01, 0,0,0); \
  acc10 = __builtin_amdgcn_mfma_f32_32x32x16_bf16(S3, y10, acc10, 0,0,0); \
  acc11 = __builtin_amdgcn_mfma_f32_32x32x16_bf16(S3, y11, acc11, 0,0,0); }

  for (int hc = 0; hc < 4; ++hc) {
    floatx16 acc00, acc01, acc10, acc11;   // [ht][jt]
    #pragma unroll
    for (int r = 0; r < 16; ++r) { acc00[r]=0.f; acc01[r]=0.f; acc10[r]=0.f; acc11[r]=0.f; }

    // wave w owns h tiles htg0 = hc*8 + w*2 (+0,+1)
    const unsigned short* w1p0 = w1mF + (((size_t)((hc*8 + w*2)*48)) << 9) + (lane << 3);
    const unsigned short* w1p1 = w1p0 + ((size_t)48 << 9);

    ushort8 caE, caO, wxS0, wxS1, wxS2, wxS3, vxS0, vxS1, vxS2, vxS3;
    floatx4 avE0, avE1, avO0, avO1;

    // prologue: product(0)->buf0; prefetch ca/av(1), wx(0), wx(1)
    LOADCAV(caE, avE0, avE1, 0);
    LOADCAV(caO, avO0, avO1, 1);
    LOADWX(wxS0, wxS1, wxS2, wxS3, 0);
    LOADWX(vxS0, vxS1, vxS2, vxS3, 1);
    PACKWRITE(Awr0, caE, avE0, avE1);
    __syncthreads();

    for (int krp = 0; krp < 12; ++krp) {
      { // EVEN round kr = 2*krp: read buf0, write product(kr+1)->buf1
        const int kr = 2*krp;
        LOADCAV(caE, avE0, avE1, kr+2);
        PACKWRITE(Awr1, caO, avO0, avO1);
        MFMA8(0, wxS0, wxS1, wxS2, wxS3);
        if (kr < 22) LOADWX(wxS0, wxS1, wxS2, wxS3, kr+2);
        __syncthreads();
      }
      { // ODD round kr = 2*krp+1: read buf1, write product(kr+1)->buf0
        const int kr = 2*krp + 1;
        if (kr < 23) {
          LOADCAV(caO, avO0, avO1, kr+2);
          PACKWRITE(Awr0, caE, avE0, avE1);
        }
        MFMA8(1, vxS0, vxS1, vxS2, vxS3);
        if (kr < 22) LOADWX(vxS0, vxS1, vxS2, vxS3, kr+2);
        __syncthreads();
      }
    }

    // ---- epilogue per ht: tanh in-register -> GEMM2 (zero shuffle) ----
    #pragma unroll
    for (int ht = 0; ht < 2; ++ht) {
      int htg = hc*8 + w*2 + ht;
      const unsigned short* w2p = w2F2 + (((size_t)(htg*2)) << 9) + (lane << 3);
      ushort8 wf0 = *reinterpret_cast<const ushort8*>(w2p);
      ushort8 wf1 = *reinterpret_cast<const ushort8*>(w2p + 512);
      int hbase = htg*32 + 4*hi5;
      #pragma unroll
      for (int jt = 0; jt < 2; ++jt) {
        const floatx16& a = (ht==0) ? (jt==0 ? acc00 : acc01)
                                    : (jt==0 ? acc10 : acc11);
        floatx16& a2 = (jt==0) ? acc2_0 : acc2_1;
        const float* qrow = Q + (size_t)(bN + jh*64 + jt*32 + col32)*HIDc + hbase;
        unsigned hfu[2][4];
        #pragma unroll
        for (int q = 0; q < 4; ++q) {
          floatx4 qv = *reinterpret_cast<const floatx4*>(qrow + 8*q);
          floatx4 pf = *reinterpret_cast<const floatx4*>(&Pi_lds[hbase + 8*q]);
          float t0 = tanh_fast(a[q*4+0] + pf[0] + qv[0]);
          float t1 = tanh_fast(a[q*4+1] + pf[1] + qv[1]);
          float t2 = tanh_fast(a[q*4+2] + pf[2] + qv[2]);
          float t3 = tanh_fast(a[q*4+3] + pf[3] + qv[3]);
          hfu[q >> 1][(q & 1)*2 + 0] = cvt_pk(t0, t1);
          hfu[q >> 1][(q & 1)*2 + 1] = cvt_pk(t2, t3);
        }
        union { uint4v u; short8 s; } f0, f1;
        f0.u[0]=hfu[0][0]; f0.u[1]=hfu[0][1]; f0.u[2]=hfu[0][2]; f0.u[3]=hfu[0][3];
        f1.u[0]=hfu[1][0]; f1.u[1]=hfu[1][1]; f1.u[2]=hfu[1][2]; f1.u[3]=hfu[1][3];
        a2 = __builtin_amdgcn_mfma_f32_32x32x16_bf16(wf0, f0.s, a2, 0,0,0);
        a2 = __builtin_amdgcn_mfma_f32_32x32x16_bf16(wf1, f1.s, a2, 0,0,0);
      }
    }
  }
#undef LOADWX
#undef LOADCAV
#undef PACKWRITE
#undef MFMA8

  // ---- cross-wave reduction (only regs 0..7 carry L<16) ----
  #pragma unroll
  for (int q = 0; q < 2; ++q) {
    floatx4 v0 = { acc2_0[q*4+0], acc2_0[q*4+1], acc2_0[q*4+2], acc2_0[q*4+3] };
    floatx4 v1 = { acc2_1[q*4+0], acc2_1[q*4+1], acc2_1[q*4+2], acc2_1[q*4+3] };
    *reinterpret_cast<floatx4*>(&red[(w*2 + 0)*2 + q][lane][0]) = v0;
    *reinterpret_cast<floatx4*>(&red[(w*2 + 1)*2 + q][lane][0]) = v1;
  }
  __syncthreads();
  {
    int jtR = w & 1, qR = w >> 1;
    floatx4 s = {0.f,0.f,0.f,0.f};
    #pragma unroll
    for (int src = 0; src < 4; ++src) {
      floatx4 v = *reinterpret_cast<const floatx4*>(&red[(src*2 + jtR)*2 + qR][lane][0]);
      s[0]+=v[0]; s[1]+=v[1]; s[2]+=v[2]; s[3]+=v[3];
    }
    int jout = jh*64 + jtR*32 + col32;
    int Lb = 8*qR + 4*hi5;
    float* op = out + ((size_t)bi*Nc + jout)*Lc + Lb;
    #pragma unroll
    for (int c = 0; c < 4; ++c) op[c] = s[c] + b2v[Lb + c];
  }
}

extern "C" void kernel_launch(void* const* d_in, const int* in_sizes, int n_in,
                              void* d_out, int out_size, void* d_ws, size_t ws_size,
                              hipStream_t stream) {
  const float* AH = (const float*)d_in[0];
  const int*   ST = (const int*)d_in[1];
  const float* W1 = (const float*)d_in[2];
  const float* b1 = (const float*)d_in[3];
  const float* W2 = (const float*)d_in[4];
  const float* b2 = (const float*)d_in[5];
  float* out = (float*)d_out;

  char* ws = (char*)d_ws;
  unsigned short* con  = (unsigned short*)ws;                //   786,432 B
  unsigned short* w1mF = (unsigned short*)(ws +   786432);   // 1,572,864 B
  unsigned short* wPQF = (unsigned short*)(ws +  2359296);   // 3,145,728 B
  float* P = (float*)(ws + 5505024);                         // 2,097,152 B
  float* Q = (float*)(ws + 7602176);                         // 2,097,152 B
  unsigned short* w2F2 = (unsigned short*)(ws + 9699328);    //    65,536 B

  k_prep<<<1680, 256, 0, stream>>>(AH, ST, W1, W2, con, w1mF, w2F2, wPQF);
  k_pq<<<256, 256, 0, stream>>>(con, wPQF, P, Q);
  k_main<<<1024, 256, 0, stream>>>(con, w1mF, w2F2, P, Q, b1, b2, out);
}